// Round 4
// baseline (4284.800 us; speedup 1.0000x reference)
//
#include <hip/hip_runtime.h>
#include <hip/hip_bf16.h>
#include <cstddef>

// Problem constants (B=4, N=4096, D=1024, H=16, HD=64, 44 dyadic offsets)
#define BATCH 4
#define SEQ   4096
#define DIM   1024
#define NHEAD 16
#define HDIM  64
#define NOFF  44

static constexpr int OFFS[NOFF] = {
    0, 1, 2, 3,
    0, 2, 4, 6,
    0, 4, 8, 12,
    0, 8, 16, 24,
    0, 16, 32, 48,
    0, 32, 64, 96,
    0, 64, 128, 192,
    0, 128, 256, 384,
    0, 256, 512, 768,
    0, 512, 1024, 1536,
    0, 1024, 2048, 3072
};

// ---------------------------------------------------------------------------
// fp32 tiled GEMM: C[M,Nn] = op(A[M,K] (optionally * A2 elementwise)) @ B[K,Nn] + bias
// MODE 0: C = A@B + bias
// MODE 1: C = sigmoid(A@B + bias)
// MODE 2: C = (A .* A2)@B + bias        (A2 shares ldA with A)
// Explicit leading dims (elements): ldA for A/A2 rows, ldB for B rows,
// ldC for C rows. Tile 128x128, BK=8, 256 threads, 8x8 micro-tile/thread.
// ---------------------------------------------------------------------------
#define BM 128
#define BN 128
#define BK 8

template <int MODE>
__launch_bounds__(256)
__global__ void gemm_k(const float* __restrict__ A, const float* __restrict__ A2,
                       const float* __restrict__ Bm, const float* __restrict__ bias,
                       float* __restrict__ C, int M, int Nn, int K,
                       int ldA, int ldB, int ldC) {
    __shared__ float As[BK][BM];   // A transposed in LDS
    __shared__ float Bs[BK][BN];

    const int tid = threadIdx.x;
    const int m0 = blockIdx.y * BM;
    const int n0 = blockIdx.x * BN;
    const int tx = tid & 15;        // 0..15  -> col group
    const int ty = tid >> 4;        // 0..15  -> row group

    float acc[8][8] = {};

    // A-tile loader: 128 rows x 8 cols, one float4 per thread
    const int arow = tid >> 1;          // 0..127
    const int ac4  = (tid & 1) * 4;     // 0 or 4
    // B-tile loader: 8 rows x 128 cols, one float4 per thread
    const int brow = tid >> 5;          // 0..7
    const int bc4  = (tid & 31) * 4;    // 0..124

    const float* Aptr  = A + (size_t)(m0 + arow) * ldA + ac4;
    const float* A2ptr = (MODE == 2) ? (A2 + (size_t)(m0 + arow) * ldA + ac4) : nullptr;
    const float* Bptr  = Bm + (size_t)brow * ldB + n0 + bc4;

    for (int k0 = 0; k0 < K; k0 += BK) {
        float4 av = *(const float4*)(Aptr + k0);
        if constexpr (MODE == 2) {
            float4 gv = *(const float4*)(A2ptr + k0);
            av.x *= gv.x; av.y *= gv.y; av.z *= gv.z; av.w *= gv.w;
        }
        float4 bv = *(const float4*)(Bptr + (size_t)k0 * ldB);

        __syncthreads();   // previous iteration's reads done before overwrite
        As[ac4 + 0][arow] = av.x;
        As[ac4 + 1][arow] = av.y;
        As[ac4 + 2][arow] = av.z;
        As[ac4 + 3][arow] = av.w;
        *(float4*)&Bs[brow][bc4] = bv;
        __syncthreads();

#pragma unroll
        for (int kk = 0; kk < BK; ++kk) {
            float a[8], b[8];
            *(float4*)(a)     = *(const float4*)&As[kk][ty * 8];
            *(float4*)(a + 4) = *(const float4*)&As[kk][ty * 8 + 4];
            *(float4*)(b)     = *(const float4*)&Bs[kk][tx * 8];
            *(float4*)(b + 4) = *(const float4*)&Bs[kk][tx * 8 + 4];
#pragma unroll
            for (int i = 0; i < 8; ++i)
#pragma unroll
                for (int j = 0; j < 8; ++j)
                    acc[i][j] += a[i] * b[j];
        }
    }

#pragma unroll
    for (int i = 0; i < 8; ++i) {
        const int row = m0 + ty * 8 + i;
        float* Crow = C + (size_t)row * ldC + n0 + tx * 8;
#pragma unroll
        for (int j = 0; j < 8; ++j) {
            float v = acc[i][j] + bias[n0 + tx * 8 + j];
            if constexpr (MODE == 1) v = 1.0f / (1.0f + expf(-v));
            Crow[j] = v;
        }
    }
}

// ---------------------------------------------------------------------------
// Attention over the 44 dyadic offsets for ONE batch.
// One wave per (h,n); lane = head dim.
// qkv layout: [N, 3*DIM] (q at col 0, k at col DIM, v at col 2*DIM)
// gathered is written IN-PLACE over the q columns (each wave reads its own q
// slot before overwriting it; k/v columns are untouched).
// ---------------------------------------------------------------------------
__launch_bounds__(256)
__global__ void attn_k(float* __restrict__ qkv,
                       const float* __restrict__ pos_bias) {
    const float scale = 0.125f;  // 64^-0.5

    const int w    = blockIdx.x * 4 + (threadIdx.x >> 6);
    const int lane = threadIdx.x & 63;
    const int n = w & (SEQ - 1);     // 0..4095
    const int h = w >> 12;           // 0..15

    const size_t qidx = (size_t)n * (3 * DIM) + h * HDIM + lane;
    const float qv = qkv[qidx];
    const int kcol = DIM + h * HDIM + lane;
    const int vcol = 2 * DIM + h * HDIM + lane;

    float sc[NOFF];

#pragma unroll
    for (int o = 0; o < NOFF; ++o) {
        const int off = OFFS[o];
        const float pb = pos_bias[o * NHEAD + h];
        float s;
        if (off <= n) {
            float p = qv * qkv[(size_t)(n - off) * (3 * DIM) + kcol];
            p += __shfl_xor(p, 1);
            p += __shfl_xor(p, 2);
            p += __shfl_xor(p, 4);
            p += __shfl_xor(p, 8);
            p += __shfl_xor(p, 16);
            p += __shfl_xor(p, 32);
            s = p * scale + pb;
        } else {
            s = pb;  // shifted k is zero-padded -> dot = 0
        }
        sc[o] = s;
    }

    // softmax over the 44 entries (all lanes hold identical sc[])
    float mx = sc[0];
#pragma unroll
    for (int o = 1; o < NOFF; ++o) mx = fmaxf(mx, sc[o]);
    float sum = 0.f;
#pragma unroll
    for (int o = 0; o < NOFF; ++o) {
        sc[o] = expf(sc[o] - mx);
        sum += sc[o];
    }
    const float inv = 1.0f / sum;

    float acc = 0.f;
#pragma unroll
    for (int o = 0; o < NOFF; ++o) {
        const int off = OFFS[o];
        if (off <= n)
            acc += sc[o] * qkv[(size_t)(n - off) * (3 * DIM) + vcol];
    }
    acc *= inv;

    qkv[qidx] = acc;   // gathered, in-place over q
}

// ---------------------------------------------------------------------------
// Per-batch pipeline; workspace high-water = ONE interleaved qkv buffer
// [4096, 3072] = 48 MB. After attention:
//   q-cols  (0..1023)    <- gathered   (written in-place by attn_k)
//   k-cols  (1024..2047) <- gate       (gate GEMM runs after attn, stream-ordered)
// Final GEMM reads both with ldA = 3072.
// ---------------------------------------------------------------------------
extern "C" void kernel_launch(void* const* d_in, const int* in_sizes, int n_in,
                              void* d_out, int out_size, void* d_ws, size_t ws_size,
                              hipStream_t stream) {
    const float* x        = (const float*)d_in[0];
    const float* w_qkv    = (const float*)d_in[1];
    const float* b_qkv    = (const float*)d_in[2];
    const float* w_out    = (const float*)d_in[3];
    const float* b_out    = (const float*)d_in[4];
    const float* w_gate   = (const float*)d_in[5];
    const float* b_gate   = (const float*)d_in[6];
    const float* pos_bias = (const float*)d_in[7];
    float* out = (float*)d_out;

    const int Mb = SEQ;                       // 4096 rows per batch
    float* qkv_b = (float*)d_ws;              // [4096, 3072]  48 MB total

    for (int b = 0; b < BATCH; ++b) {
        const float* xb   = x   + (size_t)b * SEQ * DIM;
        float*       outb = out + (size_t)b * SEQ * DIM;

        // 1) qkv_b = x_b @ w_qkv + b_qkv        [4096, 3072]
        gemm_k<0><<<dim3(3 * DIM / BN, Mb / BM), 256, 0, stream>>>(
            xb, nullptr, w_qkv, b_qkv, qkv_b,
            Mb, 3 * DIM, DIM, DIM, 3 * DIM, 3 * DIM);

        // 2) dyadic-offset attention; gathered overwrites q-cols in place
        attn_k<<<(NHEAD * SEQ) / 4, 256, 0, stream>>>(qkv_b, pos_bias);

        // 3) gate = sigmoid(x_b @ w_gate + b_gate) -> k-cols of qkv_b
        gemm_k<1><<<dim3(DIM / BN, Mb / BM), 256, 0, stream>>>(
            xb, nullptr, w_gate, b_gate, qkv_b + DIM,
            Mb, DIM, DIM, DIM, DIM, 3 * DIM);

        // 4) out_b = (gathered .* gate) @ w_out + b_out
        gemm_k<2><<<dim3(DIM / BN, Mb / BM), 256, 0, stream>>>(
            qkv_b, qkv_b + DIM, w_out, b_out, outb,
            Mb, DIM, DIM, 3 * DIM, DIM, DIM);
    }
}

// Round 7
// 1520.215 us; speedup vs baseline: 2.8185x; 2.8185x over previous
//
#include <hip/hip_runtime.h>
#include <hip/hip_bf16.h>
#include <cstddef>
#include <cstdint>

// Problem constants (B=4, N=4096, D=1024, H=16, HD=64, 44 dyadic offsets)
#define BATCH 4
#define SEQ   4096
#define DIM   1024
#define NHEAD 16
#define HDIM  64
#define NOFF  44
#define NDIS  24   // distinct offsets

static constexpr int OFFS[NOFF] = {
    0, 1, 2, 3,
    0, 2, 4, 6,
    0, 4, 8, 12,
    0, 8, 16, 24,
    0, 16, 32, 48,
    0, 32, 64, 96,
    0, 64, 128, 192,
    0, 128, 256, 384,
    0, 256, 512, 768,
    0, 512, 1024, 1536,
    0, 1024, 2048, 3072
};
static constexpr int DOFF[NDIS] = {
    0,1,2,3,4,6,8,12,16,24,32,48,64,96,128,192,256,384,512,768,1024,1536,2048,3072
};
static constexpr int MAP[NOFF] = {
    0,1,2,3,
    0,2,4,5,
    0,4,6,7,
    0,6,8,9,
    0,8,10,11,
    0,10,12,13,
    0,12,14,15,
    0,14,16,17,
    0,16,18,19,
    0,18,20,21,
    0,20,22,23
};

typedef short bf16x8 __attribute__((ext_vector_type(8)));
typedef float f32x4  __attribute__((ext_vector_type(4)));

__device__ __forceinline__ unsigned short f2bf(float f) {
    unsigned int u = __float_as_uint(f);
    u += 0x7FFFu + ((u >> 16) & 1u);          // RNE
    return (unsigned short)(u >> 16);
}
__device__ __forceinline__ float bf2f(unsigned short h) {
    return __uint_as_float(((unsigned int)h) << 16);
}

#define GLOAD_LDS16(g, l)                                                     \
    __builtin_amdgcn_global_load_lds(                                         \
        (const __attribute__((address_space(1))) void*)(g),                   \
        (__attribute__((address_space(3))) void*)(l), 16, 0, 0)

// ===========================================================================
// FAST PATH
// ===========================================================================

// --- weight prep: W[K=1024][Nw] fp32  ->  WT_hi[Nw][1024] bf16 (+ optional lo)
__launch_bounds__(256)
__global__ void prep_w(const float* __restrict__ W, unsigned short* __restrict__ Th,
                       unsigned short* __restrict__ Tl, int Nw) {
    __shared__ float t[32][33];
    const int nb = blockIdx.x * 32;   // col tile in W
    const int kb = blockIdx.y * 32;   // row tile in W
    const int c  = threadIdx.x & 31;
    const int r0 = threadIdx.x >> 5;  // 0..7
#pragma unroll
    for (int i = 0; i < 4; ++i) {
        const int r = r0 + i * 8;
        t[r][c] = W[(size_t)(kb + r) * Nw + nb + c];
    }
    __syncthreads();
#pragma unroll
    for (int i = 0; i < 4; ++i) {
        const int rr = r0 + i * 8;                // row in T tile (col in W)
        const float v = t[c][rr];                 // = W[kb+c][nb+rr]
        const unsigned short h = f2bf(v);
        const size_t oidx = (size_t)(nb + rr) * 1024 + kb + c;
        Th[oidx] = h;
        if (Tl) Tl[oidx] = f2bf(v - bf2f(h));
    }
}

// --- x fp32 -> bf16 (hi only)
__launch_bounds__(256)
__global__ void split_x(const float* __restrict__ X, unsigned short* __restrict__ H) {
    const size_t i = ((size_t)blockIdx.x * 256 + threadIdx.x) * 4;
    const float4 v = *(const float4*)(X + i);
    ushort4 o;
    o.x = f2bf(v.x); o.y = f2bf(v.y); o.z = f2bf(v.z); o.w = f2bf(v.w);
    *(ushort4*)(H + i) = o;
}

// --- MFMA GEMM.  C[M,Nn] = A[M,1024] @ B^T[Nn,1024]^T + bias, all bf16 inputs.
// TERMS==3: 3-term split (Ah+Al)(Bh+Bl) minus lo*lo, fp32-class accuracy.
// EPI: 0 = store bf16, 1 = sigmoid -> bf16, 2 = store fp32.
// 256 threads = 4 waves (2x2), tile 128x128, K-step 32, each wave 64x64 quad.
//
// LDS bank-conflict swizzle (rule #21: gload_lds writes linearly, so the
// permutation is applied to the per-lane GLOBAL source and mirrored on the
// ds_read side):  global (row, 16B-slice c) -> LDS slice c' = (c + ((row&15)>>1)) & 3.
// Fragment-read slot occupancy becomes 2 lanes/slot = conflict-free (m136).
template <int EPI, int TERMS>
__launch_bounds__(256)
__global__ void mfma_gemm(const unsigned short* __restrict__ Ah,
                          const unsigned short* __restrict__ Al,
                          const unsigned short* __restrict__ Bth,
                          const unsigned short* __restrict__ Btl,
                          const float* __restrict__ bias,
                          unsigned short* __restrict__ Cb,
                          float* __restrict__ Cf,
                          int ldC) {
    constexpr int K = 1024;
    __shared__ alignas(16) unsigned short sAh[128][32];
    __shared__ alignas(16) unsigned short sBh[128][32];
    __shared__ alignas(16) unsigned short sAl[(TERMS == 3) ? 128 : 1][32];
    __shared__ alignas(16) unsigned short sBl[(TERMS == 3) ? 128 : 1][32];

    const int tid  = threadIdx.x;
    const int lane = tid & 63;
    const int wid  = tid >> 6;          // 0..3
    const int wr   = wid >> 1;          // 0..1
    const int wc   = wid & 1;

    const int m0 = blockIdx.y * 128;
    const int n0 = blockIdx.x * 128;

    // staging geometry: wave stages rows [wid*32, wid*32+32) in two 16-row chunks.
    // Lane l writes LDS linearly at (row = chunk + (l>>2), slice = l&3); the
    // global source slice is inverse-swizzled so that LDS holds the permuted layout.
    const int srow = wid * 32 + (lane >> 2);
    const int scol = (((lane & 3) - ((lane >> 3) & 3)) & 3) * 8;  // elements

    const unsigned short* gA = Ah + (size_t)(m0 + srow) * K + scol;
    const unsigned short* gB = Bth + (size_t)(n0 + srow) * K + scol;
    const unsigned short* gAl = (TERMS == 3) ? Al + (size_t)(m0 + srow) * K + scol : nullptr;
    const unsigned short* gBl = (TERMS == 3) ? Btl + (size_t)(n0 + srow) * K + scol : nullptr;

    // fragment-read swizzled column (elements): slice (lane>>4) of row (lane&15)
    const int r15 = lane & 15;
    const int csw = ((((lane >> 4) + (r15 >> 1)) & 3)) * 8;

    f32x4 acc[4][4] = {};

    for (int k0 = 0; k0 < K; k0 += 32) {
        __syncthreads();   // previous compute done before overwrite
        GLOAD_LDS16(gA + k0,             &sAh[wid * 32][0]);
        GLOAD_LDS16(gA + 16 * K + k0,    &sAh[wid * 32 + 16][0]);
        GLOAD_LDS16(gB + k0,             &sBh[wid * 32][0]);
        GLOAD_LDS16(gB + 16 * K + k0,    &sBh[wid * 32 + 16][0]);
        if constexpr (TERMS == 3) {
            GLOAD_LDS16(gAl + k0,          &sAl[wid * 32][0]);
            GLOAD_LDS16(gAl + 16 * K + k0, &sAl[wid * 32 + 16][0]);
            GLOAD_LDS16(gBl + k0,          &sBl[wid * 32][0]);
            GLOAD_LDS16(gBl + 16 * K + k0, &sBl[wid * 32 + 16][0]);
        }
        __syncthreads();   // barrier drains vmcnt -> LDS tiles visible

        bf16x8 afh[4], bfh[4];
#pragma unroll
        for (int i = 0; i < 4; ++i) {
            afh[i] = *(const bf16x8*)&sAh[wr * 64 + i * 16 + r15][csw];
            bfh[i] = *(const bf16x8*)&sBh[wc * 64 + i * 16 + r15][csw];
        }
        if constexpr (TERMS == 3) {
            bf16x8 afl[4], bfl[4];
#pragma unroll
            for (int i = 0; i < 4; ++i) {
                afl[i] = *(const bf16x8*)&sAl[wr * 64 + i * 16 + r15][csw];
                bfl[i] = *(const bf16x8*)&sBl[wc * 64 + i * 16 + r15][csw];
            }
#pragma unroll
            for (int mi = 0; mi < 4; ++mi)
#pragma unroll
                for (int ni = 0; ni < 4; ++ni) {
                    acc[mi][ni] = __builtin_amdgcn_mfma_f32_16x16x32_bf16(afh[mi], bfh[ni], acc[mi][ni], 0, 0, 0);
                    acc[mi][ni] = __builtin_amdgcn_mfma_f32_16x16x32_bf16(afh[mi], bfl[ni], acc[mi][ni], 0, 0, 0);
                    acc[mi][ni] = __builtin_amdgcn_mfma_f32_16x16x32_bf16(afl[mi], bfh[ni], acc[mi][ni], 0, 0, 0);
                }
        } else {
#pragma unroll
            for (int mi = 0; mi < 4; ++mi)
#pragma unroll
                for (int ni = 0; ni < 4; ++ni)
                    acc[mi][ni] = __builtin_amdgcn_mfma_f32_16x16x32_bf16(afh[mi], bfh[ni], acc[mi][ni], 0, 0, 0);
        }
    }

    // epilogue: C/D layout col = lane&15, row = (lane>>4)*4 + j  [m89/m91]
    const int colb = n0 + wc * 64 + (lane & 15);
    const int rowb = m0 + wr * 64 + (lane >> 4) * 4;
#pragma unroll
    for (int ni = 0; ni < 4; ++ni) {
        const int col = colb + ni * 16;
        const float bcol = bias[col];
#pragma unroll
        for (int mi = 0; mi < 4; ++mi) {
#pragma unroll
            for (int j = 0; j < 4; ++j) {
                const int row = rowb + mi * 16 + j;
                float o = acc[mi][ni][j] + bcol;
                if constexpr (EPI == 1) o = 1.0f / (1.0f + expf(-o));
                if constexpr (EPI == 2) Cf[(size_t)row * ldC + col] = o;
                else                    Cb[(size_t)row * ldC + col] = f2bf(o);
            }
        }
    }
}

// --- attention over 24 DISTINCT offsets, bf16 qkv, fused gate-multiply,
//     writes product hi/lo bf16 for the split out-GEMM.
__launch_bounds__(256)
__global__ void attn2(const unsigned short* __restrict__ qkvb,
                      const unsigned short* __restrict__ gateb,
                      const float* __restrict__ pos_bias,
                      unsigned short* __restrict__ Jh,
                      unsigned short* __restrict__ Jl) {
    const float scale = 0.125f;  // 64^-0.5
    const int w    = blockIdx.x * 4 + (threadIdx.x >> 6);
    const int lane = threadIdx.x & 63;
    const int n = w & (SEQ - 1);
    const int h = w >> 12;
    const int colq = h * HDIM + lane;

    const float q = bf2f(qkvb[(size_t)n * (3 * DIM) + colq]);

    float dots[NDIS];
#pragma unroll
    for (int d = 0; d < NDIS; ++d) {
        const int off = DOFF[d];
        float p = 0.f;
        if (off <= n) {
            p = q * bf2f(qkvb[(size_t)(n - off) * (3 * DIM) + DIM + colq]);
            p += __shfl_xor(p, 1);
            p += __shfl_xor(p, 2);
            p += __shfl_xor(p, 4);
            p += __shfl_xor(p, 8);
            p += __shfl_xor(p, 16);
            p += __shfl_xor(p, 32);
        }
        dots[d] = p;
    }

    float sc[NOFF];
    float mx = -1e30f;
#pragma unroll
    for (int o = 0; o < NOFF; ++o) {
        sc[o] = dots[MAP[o]] * scale + pos_bias[o * NHEAD + h];
        mx = fmaxf(mx, sc[o]);
    }
    float Z = 0.f;
#pragma unroll
    for (int o = 0; o < NOFF; ++o) {
        sc[o] = expf(sc[o] - mx);
        Z += sc[o];
    }
    float W[NDIS] = {};
#pragma unroll
    for (int o = 0; o < NOFF; ++o) W[MAP[o]] += sc[o];

    float acc = 0.f;
#pragma unroll
    for (int d = 0; d < NDIS; ++d) {
        const int off = DOFF[d];
        if (off <= n)
            acc += W[d] * bf2f(qkvb[(size_t)(n - off) * (3 * DIM) + 2 * DIM + colq]);
    }

    const float g = bf2f(gateb[(size_t)n * DIM + colq]);
    const float p = acc * (1.0f / Z) * g;
    const unsigned short hb = f2bf(p);
    const size_t oidx = (size_t)n * DIM + colq;
    Jh[oidx] = hb;
    Jl[oidx] = f2bf(p - bf2f(hb));
}

// ===========================================================================
// FALLBACK PATH (proven R4 fp32 pipeline, needs 48 MB ws)
// ===========================================================================
#define BM 128
#define BN 128
#define BK 8

template <int MODE>
__launch_bounds__(256)
__global__ void gemm_k(const float* __restrict__ A, const float* __restrict__ A2,
                       const float* __restrict__ Bm, const float* __restrict__ bias,
                       float* __restrict__ C, int M, int Nn, int Kk,
                       int ldA, int ldB, int ldC) {
    __shared__ float As[BK][BM];
    __shared__ float Bs[BK][BN];
    const int tid = threadIdx.x;
    const int m0 = blockIdx.y * BM;
    const int n0 = blockIdx.x * BN;
    const int tx = tid & 15;
    const int ty = tid >> 4;
    float acc[8][8] = {};
    const int arow = tid >> 1;
    const int ac4  = (tid & 1) * 4;
    const int brow = tid >> 5;
    const int bc4  = (tid & 31) * 4;
    const float* Aptr  = A + (size_t)(m0 + arow) * ldA + ac4;
    const float* A2ptr = (MODE == 2) ? (A2 + (size_t)(m0 + arow) * ldA + ac4) : nullptr;
    const float* Bptr  = Bm + (size_t)brow * ldB + n0 + bc4;
    for (int k0 = 0; k0 < Kk; k0 += BK) {
        float4 av = *(const float4*)(Aptr + k0);
        if constexpr (MODE == 2) {
            float4 gv = *(const float4*)(A2ptr + k0);
            av.x *= gv.x; av.y *= gv.y; av.z *= gv.z; av.w *= gv.w;
        }
        float4 bv = *(const float4*)(Bptr + (size_t)k0 * ldB);
        __syncthreads();
        As[ac4 + 0][arow] = av.x;
        As[ac4 + 1][arow] = av.y;
        As[ac4 + 2][arow] = av.z;
        As[ac4 + 3][arow] = av.w;
        *(float4*)&Bs[brow][bc4] = bv;
        __syncthreads();
#pragma unroll
        for (int kk = 0; kk < BK; ++kk) {
            float a[8], b[8];
            *(float4*)(a)     = *(const float4*)&As[kk][ty * 8];
            *(float4*)(a + 4) = *(const float4*)&As[kk][ty * 8 + 4];
            *(float4*)(b)     = *(const float4*)&Bs[kk][tx * 8];
            *(float4*)(b + 4) = *(const float4*)&Bs[kk][tx * 8 + 4];
#pragma unroll
            for (int i = 0; i < 8; ++i)
#pragma unroll
                for (int j = 0; j < 8; ++j)
                    acc[i][j] += a[i] * b[j];
        }
    }
#pragma unroll
    for (int i = 0; i < 8; ++i) {
        const int row = m0 + ty * 8 + i;
        float* Crow = C + (size_t)row * ldC + n0 + tx * 8;
#pragma unroll
        for (int j = 0; j < 8; ++j) {
            float v = acc[i][j] + bias[n0 + tx * 8 + j];
            if constexpr (MODE == 1) v = 1.0f / (1.0f + expf(-v));
            Crow[j] = v;
        }
    }
}

__launch_bounds__(256)
__global__ void attn_k(float* __restrict__ qkv, const float* __restrict__ pos_bias) {
    const float scale = 0.125f;
    const int w    = blockIdx.x * 4 + (threadIdx.x >> 6);
    const int lane = threadIdx.x & 63;
    const int n = w & (SEQ - 1);
    const int h = w >> 12;
    const size_t qidx = (size_t)n * (3 * DIM) + h * HDIM + lane;
    const float qv = qkv[qidx];
    const int kcol = DIM + h * HDIM + lane;
    const int vcol = 2 * DIM + h * HDIM + lane;
    float sc[NOFF];
#pragma unroll
    for (int o = 0; o < NOFF; ++o) {
        const int off = OFFS[o];
        const float pb = pos_bias[o * NHEAD + h];
        float s;
        if (off <= n) {
            float p = qv * qkv[(size_t)(n - off) * (3 * DIM) + kcol];
            p += __shfl_xor(p, 1);
            p += __shfl_xor(p, 2);
            p += __shfl_xor(p, 4);
            p += __shfl_xor(p, 8);
            p += __shfl_xor(p, 16);
            p += __shfl_xor(p, 32);
            s = p * scale + pb;
        } else s = pb;
        sc[o] = s;
    }
    float mx = sc[0];
#pragma unroll
    for (int o = 1; o < NOFF; ++o) mx = fmaxf(mx, sc[o]);
    float sum = 0.f;
#pragma unroll
    for (int o = 0; o < NOFF; ++o) { sc[o] = expf(sc[o] - mx); sum += sc[o]; }
    const float inv = 1.0f / sum;
    float acc = 0.f;
#pragma unroll
    for (int o = 0; o < NOFF; ++o) {
        const int off = OFFS[o];
        if (off <= n) acc += sc[o] * qkv[(size_t)(n - off) * (3 * DIM) + vcol];
    }
    qkv[qidx] = acc * inv;
}

// ===========================================================================
extern "C" void kernel_launch(void* const* d_in, const int* in_sizes, int n_in,
                              void* d_out, int out_size, void* d_ws, size_t ws_size,
                              hipStream_t stream) {
    const float* x        = (const float*)d_in[0];
    const float* w_qkv    = (const float*)d_in[1];
    const float* b_qkv    = (const float*)d_in[2];
    const float* w_out    = (const float*)d_in[3];
    const float* b_out    = (const float*)d_in[4];
    const float* w_gate   = (const float*)d_in[5];
    const float* b_gate   = (const float*)d_in[6];
    const float* pos_bias = (const float*)d_in[7];
    float* out = (float*)d_out;

    const size_t FAST_WS = 62914560ull;   // 60 MiB exactly (layout below)

    if (ws_size >= FAST_WS) {
        // ---- fast path ----
        unsigned short* wqkvT  = (unsigned short*)d_ws;            // [3072][1024]
        unsigned short* wgateT = wqkvT  + (size_t)3072 * 1024;     // [1024][1024]
        unsigned short* woutTh = wgateT + (size_t)1024 * 1024;
        unsigned short* woutTl = woutTh + (size_t)1024 * 1024;
        unsigned short* xh     = woutTl + (size_t)1024 * 1024;     // [4096][1024], later J_hi
        unsigned short* gateb  = xh     + (size_t)4096 * 1024;     // [4096][1024]
        unsigned short* Jlo    = gateb  + (size_t)4096 * 1024;     // [4096][1024]
        unsigned short* qkvb   = Jlo    + (size_t)4096 * 1024;     // [4096][3072]

        prep_w<<<dim3(3072 / 32, 1024 / 32), 256, 0, stream>>>(w_qkv, wqkvT, nullptr, 3072);
        prep_w<<<dim3(1024 / 32, 1024 / 32), 256, 0, stream>>>(w_gate, wgateT, nullptr, 1024);
        prep_w<<<dim3(1024 / 32, 1024 / 32), 256, 0, stream>>>(w_out, woutTh, woutTl, 1024);

        for (int b = 0; b < BATCH; ++b) {
            const float* xb   = x   + (size_t)b * SEQ * DIM;
            float*       outb = out + (size_t)b * SEQ * DIM;

            split_x<<<4096, 256, 0, stream>>>(xb, xh);
            // qkv (bf16): [4096,3072]
            mfma_gemm<0, 1><<<dim3(3072 / 128, 4096 / 128), 256, 0, stream>>>(
                xh, nullptr, wqkvT, nullptr, b_qkv, qkvb, nullptr, 3072);
            // gate (bf16, sigmoid): [4096,1024]
            mfma_gemm<1, 1><<<dim3(1024 / 128, 4096 / 128), 256, 0, stream>>>(
                xh, nullptr, wgateT, nullptr, b_gate, gateb, nullptr, 1024);
            // attention + gate-multiply -> product hi/lo (J_hi aliases xh; x dead now)
            attn2<<<(NHEAD * SEQ) / 4, 256, 0, stream>>>(qkvb, gateb, pos_bias, xh, Jlo);
            // out = (gathered.*gate) @ w_out + b_out, 3-term split, fp32 out
            mfma_gemm<2, 3><<<dim3(1024 / 128, 4096 / 128), 256, 0, stream>>>(
                xh, Jlo, woutTh, woutTl, b_out, nullptr, outb, 1024);
        }
    } else {
        // ---- proven fp32 fallback (R4), needs 48 MB ----
        const int Mb = SEQ;
        float* qkv_b = (float*)d_ws;
        for (int b = 0; b < BATCH; ++b) {
            const float* xb   = x   + (size_t)b * SEQ * DIM;
            float*       outb = out + (size_t)b * SEQ * DIM;
            gemm_k<0><<<dim3(3 * DIM / BN, Mb / BM), 256, 0, stream>>>(
                xb, nullptr, w_qkv, b_qkv, qkv_b, Mb, 3 * DIM, DIM, DIM, 3 * DIM, 3 * DIM);
            attn_k<<<(NHEAD * SEQ) / 4, 256, 0, stream>>>(qkv_b, pos_bias);
            gemm_k<1><<<dim3(DIM / BN, Mb / BM), 256, 0, stream>>>(
                xb, nullptr, w_gate, b_gate, qkv_b + DIM, Mb, DIM, DIM, DIM, DIM, 3 * DIM);
            gemm_k<2><<<dim3(DIM / BN, Mb / BM), 256, 0, stream>>>(
                qkv_b, qkv_b + DIM, w_out, b_out, outb, Mb, DIM, DIM, 3 * DIM, DIM, DIM);
        }
    }
}

// Round 9
// 1390.219 us; speedup vs baseline: 3.0821x; 1.0935x over previous
//
#include <hip/hip_runtime.h>
#include <hip/hip_bf16.h>
#include <cstddef>
#include <cstdint>

// Problem constants (B=4, N=4096, D=1024, H=16, HD=64, 44 dyadic offsets)
#define BATCH 4
#define SEQ   4096
#define DIM   1024
#define NHEAD 16
#define HDIM  64
#define NOFF  44
#define NDIS  24   // distinct offsets

static constexpr int OFFS[NOFF] = {
    0, 1, 2, 3,
    0, 2, 4, 6,
    0, 4, 8, 12,
    0, 8, 16, 24,
    0, 16, 32, 48,
    0, 32, 64, 96,
    0, 64, 128, 192,
    0, 128, 256, 384,
    0, 256, 512, 768,
    0, 512, 1024, 1536,
    0, 1024, 2048, 3072
};
static constexpr int DOFF[NDIS] = {
    0,1,2,3,4,6,8,12,16,24,32,48,64,96,128,192,256,384,512,768,1024,1536,2048,3072
};
static constexpr int MAP[NOFF] = {
    0,1,2,3,
    0,2,4,5,
    0,4,6,7,
    0,6,8,9,
    0,8,10,11,
    0,10,12,13,
    0,12,14,15,
    0,14,16,17,
    0,16,18,19,
    0,18,20,21,
    0,20,22,23
};

typedef short bf16x8 __attribute__((ext_vector_type(8)));
typedef float f32x4  __attribute__((ext_vector_type(4)));
typedef unsigned short u16x8 __attribute__((ext_vector_type(8)));

__device__ __forceinline__ unsigned short f2bf(float f) {
    unsigned int u = __float_as_uint(f);
    u += 0x7FFFu + ((u >> 16) & 1u);          // RNE
    return (unsigned short)(u >> 16);
}
__device__ __forceinline__ float bf2f(unsigned short h) {
    return __uint_as_float(((unsigned int)h) << 16);
}

#define GLOAD_LDS16(g, l)                                                     \
    __builtin_amdgcn_global_load_lds(                                         \
        (const __attribute__((address_space(1))) void*)(g),                   \
        (__attribute__((address_space(3))) void*)(l), 16, 0, 0)

// ===========================================================================
// FAST PATH
// ===========================================================================

// --- weight prep: W[K=1024][Nw] fp32  ->  WT_hi[Nw][1024] bf16 (+ optional lo)
__launch_bounds__(256)
__global__ void prep_w(const float* __restrict__ W, unsigned short* __restrict__ Th,
                       unsigned short* __restrict__ Tl, int Nw) {
    __shared__ float t[32][33];
    const int nb = blockIdx.x * 32;   // col tile in W
    const int kb = blockIdx.y * 32;   // row tile in W
    const int c  = threadIdx.x & 31;
    const int r0 = threadIdx.x >> 5;  // 0..7
#pragma unroll
    for (int i = 0; i < 4; ++i) {
        const int r = r0 + i * 8;
        t[r][c] = W[(size_t)(kb + r) * Nw + nb + c];
    }
    __syncthreads();
#pragma unroll
    for (int i = 0; i < 4; ++i) {
        const int rr = r0 + i * 8;                // row in T tile (col in W)
        const float v = t[c][rr];                 // = W[kb+c][nb+rr]
        const unsigned short h = f2bf(v);
        const size_t oidx = (size_t)(nb + rr) * 1024 + kb + c;
        Th[oidx] = h;
        if (Tl) Tl[oidx] = f2bf(v - bf2f(h));
    }
}

// --- x fp32 -> bf16 (hi only)
__launch_bounds__(256)
__global__ void split_x(const float* __restrict__ X, unsigned short* __restrict__ H) {
    const size_t i = ((size_t)blockIdx.x * 256 + threadIdx.x) * 4;
    const float4 v = *(const float4*)(X + i);
    ushort4 o;
    o.x = f2bf(v.x); o.y = f2bf(v.y); o.z = f2bf(v.z); o.w = f2bf(v.w);
    *(ushort4*)(H + i) = o;
}

// --- MFMA GEMM.  C[M,Nn] = A[M,1024] @ B^T[Nn,1024]^T + bias, all bf16 inputs.
// TERMS==3: 3-term split (Ah+Al)(Bh+Bl) minus lo*lo, fp32-class accuracy.
// EPI: 0 = store bf16, 1 = sigmoid -> bf16, 2 = store fp32.
// BROW: 1 = bias indexed by row (for transposed-output GEMMs), 0 = by col.
// 256 threads = 4 waves (2x2), tile 128x128, K-step 32, each wave 64x64 quad.
// LDS swizzle proven R7 (SQ_LDS_BANK_CONFLICT == 0 on HW).
template <int EPI, int TERMS, int BROW>
__launch_bounds__(256)
__global__ void mfma_gemm(const unsigned short* __restrict__ Ah,
                          const unsigned short* __restrict__ Al,
                          const unsigned short* __restrict__ Bth,
                          const unsigned short* __restrict__ Btl,
                          const float* __restrict__ bias,
                          unsigned short* __restrict__ Cb,
                          float* __restrict__ Cf,
                          int ldC) {
    constexpr int K = 1024;
    __shared__ alignas(16) unsigned short sAh[128][32];
    __shared__ alignas(16) unsigned short sBh[128][32];
    __shared__ alignas(16) unsigned short sAl[(TERMS == 3) ? 128 : 1][32];
    __shared__ alignas(16) unsigned short sBl[(TERMS == 3) ? 128 : 1][32];

    const int tid  = threadIdx.x;
    const int lane = tid & 63;
    const int wid  = tid >> 6;          // 0..3
    const int wr   = wid >> 1;          // 0..1
    const int wc   = wid & 1;

    const int m0 = blockIdx.y * 128;
    const int n0 = blockIdx.x * 128;

    const int srow = wid * 32 + (lane >> 2);
    const int scol = (((lane & 3) - ((lane >> 3) & 3)) & 3) * 8;  // inverse-swizzled src slice

    const unsigned short* gA = Ah + (size_t)(m0 + srow) * K + scol;
    const unsigned short* gB = Bth + (size_t)(n0 + srow) * K + scol;
    const unsigned short* gAl = (TERMS == 3) ? Al + (size_t)(m0 + srow) * K + scol : nullptr;
    const unsigned short* gBl = (TERMS == 3) ? Btl + (size_t)(n0 + srow) * K + scol : nullptr;

    const int r15 = lane & 15;
    const int csw = ((((lane >> 4) + (r15 >> 1)) & 3)) * 8;       // swizzled read slice

    f32x4 acc[4][4] = {};

    for (int k0 = 0; k0 < K; k0 += 32) {
        __syncthreads();
        GLOAD_LDS16(gA + k0,             &sAh[wid * 32][0]);
        GLOAD_LDS16(gA + 16 * K + k0,    &sAh[wid * 32 + 16][0]);
        GLOAD_LDS16(gB + k0,             &sBh[wid * 32][0]);
        GLOAD_LDS16(gB + 16 * K + k0,    &sBh[wid * 32 + 16][0]);
        if constexpr (TERMS == 3) {
            GLOAD_LDS16(gAl + k0,          &sAl[wid * 32][0]);
            GLOAD_LDS16(gAl + 16 * K + k0, &sAl[wid * 32 + 16][0]);
            GLOAD_LDS16(gBl + k0,          &sBl[wid * 32][0]);
            GLOAD_LDS16(gBl + 16 * K + k0, &sBl[wid * 32 + 16][0]);
        }
        __syncthreads();

        bf16x8 afh[4], bfh[4];
#pragma unroll
        for (int i = 0; i < 4; ++i) {
            afh[i] = *(const bf16x8*)&sAh[wr * 64 + i * 16 + r15][csw];
            bfh[i] = *(const bf16x8*)&sBh[wc * 64 + i * 16 + r15][csw];
        }
        if constexpr (TERMS == 3) {
            bf16x8 afl[4], bfl[4];
#pragma unroll
            for (int i = 0; i < 4; ++i) {
                afl[i] = *(const bf16x8*)&sAl[wr * 64 + i * 16 + r15][csw];
                bfl[i] = *(const bf16x8*)&sBl[wc * 64 + i * 16 + r15][csw];
            }
#pragma unroll
            for (int mi = 0; mi < 4; ++mi)
#pragma unroll
                for (int ni = 0; ni < 4; ++ni) {
                    acc[mi][ni] = __builtin_amdgcn_mfma_f32_16x16x32_bf16(afh[mi], bfh[ni], acc[mi][ni], 0, 0, 0);
                    acc[mi][ni] = __builtin_amdgcn_mfma_f32_16x16x32_bf16(afh[mi], bfl[ni], acc[mi][ni], 0, 0, 0);
                    acc[mi][ni] = __builtin_amdgcn_mfma_f32_16x16x32_bf16(afl[mi], bfh[ni], acc[mi][ni], 0, 0, 0);
                }
        } else {
#pragma unroll
            for (int mi = 0; mi < 4; ++mi)
#pragma unroll
                for (int ni = 0; ni < 4; ++ni)
                    acc[mi][ni] = __builtin_amdgcn_mfma_f32_16x16x32_bf16(afh[mi], bfh[ni], acc[mi][ni], 0, 0, 0);
        }
    }

    // epilogue: C/D layout col = lane&15, row = (lane>>4)*4 + j  [m89/m91]
    const int colb = n0 + wc * 64 + (lane & 15);
    const int rowb = m0 + wr * 64 + (lane >> 4) * 4;
#pragma unroll
    for (int ni = 0; ni < 4; ++ni) {
        const int col = colb + ni * 16;
        const float bcol = BROW ? 0.f : bias[col];
#pragma unroll
        for (int mi = 0; mi < 4; ++mi) {
#pragma unroll
            for (int j = 0; j < 4; ++j) {
                const int row = rowb + mi * 16 + j;
                float o = acc[mi][ni][j] + (BROW ? bias[row] : bcol);
                if constexpr (EPI == 1) o = 1.0f / (1.0f + expf(-o));
                if constexpr (EPI == 2) Cf[(size_t)row * ldC + col] = o;
                else                    Cb[(size_t)row * ldC + col] = f2bf(o);
            }
        }
    }
}

// --- attention, transposed layout. lane = n. One wave = (head h, 64 n's).
// qkvT [3072][4096]: q rows 0..1023, k rows 1024..2047, v rows 2048..3071.
// gateT [1024][4096]. Writes JT_hi IN-PLACE over q rows, JT_lo to scratch.
// All loads/stores coalesced (consecutive lanes -> consecutive n).
__launch_bounds__(256)
__global__ void attn3(unsigned short* __restrict__ qkvT,
                      const unsigned short* __restrict__ gateT,
                      const float* __restrict__ pos_bias,
                      unsigned short* __restrict__ JTlo) {
    const int wid  = threadIdx.x >> 6;
    const int lane = threadIdx.x & 63;
    const int h  = blockIdx.x >> 4;     // 0..15
    const int nt = blockIdx.x & 15;     // 0..15
    const int n  = nt * 256 + wid * 64 + lane;

    const size_t qrow = (size_t)(h * HDIM) * SEQ;
    const size_t krow = (size_t)(DIM + h * HDIM) * SEQ;
    const size_t vrow = (size_t)(2 * DIM + h * HDIM) * SEQ;

    int idx[NDIS];
#pragma unroll
    for (int dd = 0; dd < NDIS; ++dd) idx[dd] = (n >= DOFF[dd]) ? (n - DOFF[dd]) : 0;

    float dots[NDIS];
#pragma unroll
    for (int dd = 0; dd < NDIS; ++dd) dots[dd] = 0.f;

    // QK: per d, 1 coalesced q-load + 24 coalesced k-loads + 24 FMA (lane-private)
    for (int d = 0; d < HDIM; ++d) {
        const float qd = bf2f(qkvT[qrow + (size_t)d * SEQ + n]);
        const unsigned short* kp = qkvT + krow + (size_t)d * SEQ;
#pragma unroll
        for (int dd = 0; dd < NDIS; ++dd)
            dots[dd] = fmaf(qd, bf2f(kp[idx[dd]]), dots[dd]);
    }
    // zero dots where offset exceeds n (reference: zero-padded shift -> dot = 0)
#pragma unroll
    for (int dd = 0; dd < NDIS; ++dd) if (n < DOFF[dd]) dots[dd] = 0.f;

    // lane-private softmax over the 44 taps (duplicate offsets share dots)
    const float scale = 0.125f;
    float mx = -1e30f;
#pragma unroll
    for (int o = 0; o < NOFF; ++o)
        mx = fmaxf(mx, fmaf(dots[MAP[o]], scale, pos_bias[o * NHEAD + h]));
    float Z = 0.f;
    float W[NDIS];
#pragma unroll
    for (int dd = 0; dd < NDIS; ++dd) W[dd] = 0.f;
#pragma unroll
    for (int o = 0; o < NOFF; ++o) {
        const float e = expf(fmaf(dots[MAP[o]], scale, pos_bias[o * NHEAD + h]) - mx);
        Z += e;
        W[MAP[o]] += e;
    }
    const float invZ = 1.0f / Z;
#pragma unroll
    for (int dd = 0; dd < NDIS; ++dd) W[dd] = (n >= DOFF[dd]) ? W[dd] * invZ : 0.f;

    // PV + gate + hi/lo split. In-place over q rows is safe: q[c][n] is only
    // ever read by the wave owning column n, and that wave's QK phase is done.
    for (int d = 0; d < HDIM; ++d) {
        const unsigned short* vp = qkvT + vrow + (size_t)d * SEQ;
        float od = 0.f;
#pragma unroll
        for (int dd = 0; dd < NDIS; ++dd)
            od = fmaf(W[dd], bf2f(vp[idx[dd]]), od);
        const float g = bf2f(gateT[qrow + (size_t)d * SEQ + n]);
        const float j = od * g;
        const unsigned short hi = f2bf(j);
        qkvT[qrow + (size_t)d * SEQ + n] = hi;
        JTlo[qrow + (size_t)d * SEQ + n] = f2bf(j - bf2f(hi));
    }
}

// --- transpose [1024][4096] -> [4096][1024] bf16, two buffer pairs (hi, lo).
// 64x64 tiles via LDS with XOR-swizzle (c>>3) -> ~2-way banks both phases.
__launch_bounds__(256)
__global__ void transpose_cn(const unsigned short* __restrict__ srcA, unsigned short* __restrict__ dstA,
                             const unsigned short* __restrict__ srcB, unsigned short* __restrict__ dstB) {
    __shared__ unsigned short t[64 * 64];
    const unsigned short* src = blockIdx.z ? srcB : srcA;
    unsigned short*       dst = blockIdx.z ? dstB : dstA;
    const int n0 = blockIdx.x * 64;
    const int c0 = blockIdx.y * 64;
    const int tt = threadIdx.x;
    {
        const int cr = tt >> 2;            // source row (c), 0..63
        const int nn = (tt & 3) * 16;      // source col start (n)
        const unsigned short* p = src + (size_t)(c0 + cr) * SEQ + n0 + nn;
        const u16x8 a = *(const u16x8*)p;
        const u16x8 b = *(const u16x8*)(p + 8);
        const int swz = (cr >> 3) & 7;
        *(u16x8*)&t[cr * 64 + (((nn >> 3) ^ swz) << 3)]       = a;
        *(u16x8*)&t[cr * 64 + ((((nn >> 3) + 1) ^ swz) << 3)] = b;
    }
    __syncthreads();
    {
        const int nr = tt >> 2;            // dst row (n), 0..63
        const int cc = (tt & 3) * 16;      // dst col start (c)
        u16x8 r0, r1;
#pragma unroll
        for (int j = 0; j < 8; ++j) {
            const int c = cc + j;
            r0[j] = t[c * 64 + ((((nr >> 3) ^ ((c >> 3) & 7)) << 3) | (nr & 7))];
        }
#pragma unroll
        for (int j = 0; j < 8; ++j) {
            const int c = cc + 8 + j;
            r1[j] = t[c * 64 + ((((nr >> 3) ^ ((c >> 3) & 7)) << 3) | (nr & 7))];
        }
        unsigned short* q = dst + (size_t)(n0 + nr) * DIM + c0 + cc;
        *(u16x8*)q       = r0;
        *(u16x8*)(q + 8) = r1;
    }
}

// ===========================================================================
// FALLBACK PATH (proven R4 fp32 pipeline, needs 48 MB ws)
// ===========================================================================
#define BM 128
#define BN 128
#define BK 8

template <int MODE>
__launch_bounds__(256)
__global__ void gemm_k(const float* __restrict__ A, const float* __restrict__ A2,
                       const float* __restrict__ Bm, const float* __restrict__ bias,
                       float* __restrict__ C, int M, int Nn, int Kk,
                       int ldA, int ldB, int ldC) {
    __shared__ float As[BK][BM];
    __shared__ float Bs[BK][BN];
    const int tid = threadIdx.x;
    const int m0 = blockIdx.y * BM;
    const int n0 = blockIdx.x * BN;
    const int tx = tid & 15;
    const int ty = tid >> 4;
    float acc[8][8] = {};
    const int arow = tid >> 1;
    const int ac4  = (tid & 1) * 4;
    const int brow = tid >> 5;
    const int bc4  = (tid & 31) * 4;
    const float* Aptr  = A + (size_t)(m0 + arow) * ldA + ac4;
    const float* A2ptr = (MODE == 2) ? (A2 + (size_t)(m0 + arow) * ldA + ac4) : nullptr;
    const float* Bptr  = Bm + (size_t)brow * ldB + n0 + bc4;
    for (int k0 = 0; k0 < Kk; k0 += BK) {
        float4 av = *(const float4*)(Aptr + k0);
        if constexpr (MODE == 2) {
            float4 gv = *(const float4*)(A2ptr + k0);
            av.x *= gv.x; av.y *= gv.y; av.z *= gv.z; av.w *= gv.w;
        }
        float4 bv = *(const float4*)(Bptr + (size_t)k0 * ldB);
        __syncthreads();
        As[ac4 + 0][arow] = av.x;
        As[ac4 + 1][arow] = av.y;
        As[ac4 + 2][arow] = av.z;
        As[ac4 + 3][arow] = av.w;
        *(float4*)&Bs[brow][bc4] = bv;
        __syncthreads();
#pragma unroll
        for (int kk = 0; kk < BK; ++kk) {
            float a[8], b[8];
            *(float4*)(a)     = *(const float4*)&As[kk][ty * 8];
            *(float4*)(a + 4) = *(const float4*)&As[kk][ty * 8 + 4];
            *(float4*)(b)     = *(const float4*)&Bs[kk][tx * 8];
            *(float4*)(b + 4) = *(const float4*)&Bs[kk][tx * 8 + 4];
#pragma unroll
            for (int i = 0; i < 8; ++i)
#pragma unroll
                for (int j = 0; j < 8; ++j)
                    acc[i][j] += a[i] * b[j];
        }
    }
#pragma unroll
    for (int i = 0; i < 8; ++i) {
        const int row = m0 + ty * 8 + i;
        float* Crow = C + (size_t)row * ldC + n0 + tx * 8;
#pragma unroll
        for (int j = 0; j < 8; ++j) {
            float v = acc[i][j] + bias[n0 + tx * 8 + j];
            if constexpr (MODE == 1) v = 1.0f / (1.0f + expf(-v));
            Crow[j] = v;
        }
    }
}

__launch_bounds__(256)
__global__ void attn_k(float* __restrict__ qkv, const float* __restrict__ pos_bias) {
    const float scale = 0.125f;
    const int w    = blockIdx.x * 4 + (threadIdx.x >> 6);
    const int lane = threadIdx.x & 63;
    const int n = w & (SEQ - 1);
    const int h = w >> 12;
    const size_t qidx = (size_t)n * (3 * DIM) + h * HDIM + lane;
    const float qv = qkv[qidx];
    const int kcol = DIM + h * HDIM + lane;
    const int vcol = 2 * DIM + h * HDIM + lane;
    float sc[NOFF];
#pragma unroll
    for (int o = 0; o < NOFF; ++o) {
        const int off = OFFS[o];
        const float pb = pos_bias[o * NHEAD + h];
        float s;
        if (off <= n) {
            float p = qv * qkv[(size_t)(n - off) * (3 * DIM) + kcol];
            p += __shfl_xor(p, 1);
            p += __shfl_xor(p, 2);
            p += __shfl_xor(p, 4);
            p += __shfl_xor(p, 8);
            p += __shfl_xor(p, 16);
            p += __shfl_xor(p, 32);
            s = p * scale + pb;
        } else s = pb;
        sc[o] = s;
    }
    float mx = sc[0];
#pragma unroll
    for (int o = 1; o < NOFF; ++o) mx = fmaxf(mx, sc[o]);
    float sum = 0.f;
#pragma unroll
    for (int o = 0; o < NOFF; ++o) { sc[o] = expf(sc[o] - mx); sum += sc[o]; }
    const float inv = 1.0f / sum;
    float acc = 0.f;
#pragma unroll
    for (int o = 0; o < NOFF; ++o) {
        const int off = OFFS[o];
        if (off <= n) acc += sc[o] * qkv[(size_t)(n - off) * (3 * DIM) + vcol];
    }
    qkv[qidx] = acc * inv;
}

// ===========================================================================
extern "C" void kernel_launch(void* const* d_in, const int* in_sizes, int n_in,
                              void* d_out, int out_size, void* d_ws, size_t ws_size,
                              hipStream_t stream) {
    const float* x        = (const float*)d_in[0];
    const float* w_qkv    = (const float*)d_in[1];
    const float* b_qkv    = (const float*)d_in[2];
    const float* w_out    = (const float*)d_in[3];
    const float* b_out    = (const float*)d_in[4];
    const float* w_gate   = (const float*)d_in[5];
    const float* b_gate   = (const float*)d_in[6];
    const float* pos_bias = (const float*)d_in[7];
    float* out = (float*)d_out;

    const size_t FAST_WS = 62914560ull;   // 60 MiB exactly (proven available in R7)

    if (ws_size >= FAST_WS) {
        // ---- fast path workspace (exactly 60 MiB) ----
        unsigned short* wqkvT  = (unsigned short*)d_ws;            // [3072][1024]  6 MiB
        unsigned short* wgateT = wqkvT  + (size_t)3072 * 1024;     // [1024][1024]  2 MiB
        unsigned short* woutTh = wgateT + (size_t)1024 * 1024;     //               2 MiB
        unsigned short* woutTl = woutTh + (size_t)1024 * 1024;     //               2 MiB
        unsigned short* xh     = woutTl + (size_t)1024 * 1024;     // [4096][1024]  8 MiB
        unsigned short* qkvT   = xh     + (size_t)4096 * 1024;     // [3072][4096] 24 MiB
        unsigned short* gateT  = qkvT   + (size_t)3072 * 4096;     // [1024][4096]  8 MiB
        unsigned short* JTlo   = gateT  + (size_t)1024 * 4096;     // [1024][4096]  8 MiB
        // post-attn aliases (source buffers dead by then):
        unsigned short* Jh = gateT;                      // [4096][1024] over gateT
        unsigned short* Jl = qkvT + (size_t)DIM * SEQ;   // [4096][1024] over kT rows

        prep_w<<<dim3(3072 / 32, 1024 / 32), 256, 0, stream>>>(w_qkv, wqkvT, nullptr, 3072);
        prep_w<<<dim3(1024 / 32, 1024 / 32), 256, 0, stream>>>(w_gate, wgateT, nullptr, 1024);
        prep_w<<<dim3(1024 / 32, 1024 / 32), 256, 0, stream>>>(w_out, woutTh, woutTl, 1024);

        for (int b = 0; b < BATCH; ++b) {
            const float* xb   = x   + (size_t)b * SEQ * DIM;
            float*       outb = out + (size_t)b * SEQ * DIM;

            split_x<<<4096, 256, 0, stream>>>(xb, xh);
            // qkvT[c][n] = wqkvT @ xh^T  (transposed-output GEMM, bias by row)
            mfma_gemm<0, 1, 1><<<dim3(4096 / 128, 3072 / 128), 256, 0, stream>>>(
                wqkvT, nullptr, xh, nullptr, b_qkv, qkvT, nullptr, 4096);
            // gateT[c][n] = sigmoid(wgateT @ xh^T + b_gate)
            mfma_gemm<1, 1, 1><<<dim3(4096 / 128, 1024 / 128), 256, 0, stream>>>(
                wgateT, nullptr, xh, nullptr, b_gate, gateT, nullptr, 4096);
            // attention (lane=n, no cross-lane): JT_hi in-place over q rows, JT_lo scratch
            attn3<<<256, 256, 0, stream>>>(qkvT, gateT, pos_bias, JTlo);
            // JT (c-major) -> J (n-major) for the final GEMM
            transpose_cn<<<dim3(4096 / 64, 1024 / 64, 2), 256, 0, stream>>>(
                qkvT, Jh, JTlo, Jl);
            // out = J @ w_out + b_out  (3-term split, fp32 out)
            mfma_gemm<2, 3, 0><<<dim3(1024 / 128, 4096 / 128), 256, 0, stream>>>(
                Jh, Jl, woutTh, woutTl, b_out, nullptr, outb, 1024);
        }
    } else {
        // ---- proven fp32 fallback (R4), needs 48 MB ----
        const int Mb = SEQ;
        float* qkv_b = (float*)d_ws;
        for (int b = 0; b < BATCH; ++b) {
            const float* xb   = x   + (size_t)b * SEQ * DIM;
            float*       outb = out + (size_t)b * SEQ * DIM;
            gemm_k<0><<<dim3(3 * DIM / BN, Mb / BM), 256, 0, stream>>>(
                xb, nullptr, w_qkv, b_qkv, qkv_b, Mb, 3 * DIM, DIM, DIM, 3 * DIM, 3 * DIM);
            attn_k<<<(NHEAD * SEQ) / 4, 256, 0, stream>>>(qkv_b, pos_bias);
            gemm_k<1><<<dim3(DIM / BN, Mb / BM), 256, 0, stream>>>(
                xb, nullptr, w_gate, b_gate, qkv_b + DIM, Mb, DIM, DIM, DIM, DIM, 3 * DIM);
            gemm_k<2><<<dim3(DIM / BN, Mb / BM), 256, 0, stream>>>(
                qkv_b, qkv_b + DIM, w_out, b_out, outb, Mb, DIM, DIM, 3 * DIM, DIM, DIM);
        }
    }
}

// Round 10
// 1109.900 us; speedup vs baseline: 3.8605x; 1.2526x over previous
//
#include <hip/hip_runtime.h>
#include <hip/hip_bf16.h>
#include <cstddef>
#include <cstdint>

// Problem constants (B=4, N=4096, D=1024, H=16, HD=64, 44 dyadic offsets)
#define BATCH 4
#define SEQ   4096
#define DIM   1024
#define NHEAD 16
#define HDIM  64
#define NOFF  44
#define NDIS  24   // distinct offsets

static constexpr int OFFS[NOFF] = {
    0, 1, 2, 3,
    0, 2, 4, 6,
    0, 4, 8, 12,
    0, 8, 16, 24,
    0, 16, 32, 48,
    0, 32, 64, 96,
    0, 64, 128, 192,
    0, 128, 256, 384,
    0, 256, 512, 768,
    0, 512, 1024, 1536,
    0, 1024, 2048, 3072
};
static constexpr int DOFF[NDIS] = {
    0,1,2,3,4,6,8,12,16,24,32,48,64,96,128,192,256,384,512,768,1024,1536,2048,3072
};
static constexpr int MAP[NOFF] = {
    0,1,2,3,
    0,2,4,5,
    0,4,6,7,
    0,6,8,9,
    0,8,10,11,
    0,10,12,13,
    0,12,14,15,
    0,14,16,17,
    0,16,18,19,
    0,18,20,21,
    0,20,22,23
};

typedef short bf16x8 __attribute__((ext_vector_type(8)));
typedef float f32x4  __attribute__((ext_vector_type(4)));
typedef unsigned short u16x8 __attribute__((ext_vector_type(8)));

__device__ __forceinline__ unsigned short f2bf(float f) {
    unsigned int u = __float_as_uint(f);
    u += 0x7FFFu + ((u >> 16) & 1u);          // RNE
    return (unsigned short)(u >> 16);
}
__device__ __forceinline__ float bf2f(unsigned short h) {
    return __uint_as_float(((unsigned int)h) << 16);
}

#define GLOAD_LDS16(g, l)                                                     \
    __builtin_amdgcn_global_load_lds(                                         \
        (const __attribute__((address_space(1))) void*)(g),                   \
        (__attribute__((address_space(3))) void*)(l), 16, 0, 0)

// ===========================================================================
// FAST PATH
// ===========================================================================

// --- weight prep: W[K=1024][Nw] fp32  ->  WT_hi[Nw][1024] bf16 (+ optional lo)
__launch_bounds__(256)
__global__ void prep_w(const float* __restrict__ W, unsigned short* __restrict__ Th,
                       unsigned short* __restrict__ Tl, int Nw) {
    __shared__ float t[32][33];
    const int nb = blockIdx.x * 32;   // col tile in W
    const int kb = blockIdx.y * 32;   // row tile in W
    const int c  = threadIdx.x & 31;
    const int r0 = threadIdx.x >> 5;  // 0..7
#pragma unroll
    for (int i = 0; i < 4; ++i) {
        const int r = r0 + i * 8;
        t[r][c] = W[(size_t)(kb + r) * Nw + nb + c];
    }
    __syncthreads();
#pragma unroll
    for (int i = 0; i < 4; ++i) {
        const int rr = r0 + i * 8;                // row in T tile (col in W)
        const float v = t[c][rr];                 // = W[kb+c][nb+rr]
        const unsigned short h = f2bf(v);
        const size_t oidx = (size_t)(nb + rr) * 1024 + kb + c;
        Th[oidx] = h;
        if (Tl) Tl[oidx] = f2bf(v - bf2f(h));
    }
}

// --- x fp32 -> bf16 (hi only)
__launch_bounds__(256)
__global__ void split_x(const float* __restrict__ X, unsigned short* __restrict__ H) {
    const size_t i = ((size_t)blockIdx.x * 256 + threadIdx.x) * 4;
    const float4 v = *(const float4*)(X + i);
    ushort4 o;
    o.x = f2bf(v.x); o.y = f2bf(v.y); o.z = f2bf(v.z); o.w = f2bf(v.w);
    *(ushort4*)(H + i) = o;
}

// --- MFMA GEMM.  C[M,Nn] = A[M,1024] @ B^T[Nn,1024]^T + bias, all bf16 inputs.
// TERMS==3: 3-term split (Ah+Al)(Bh+Bl) minus lo*lo, fp32-class accuracy.
// EPI: 0 = store bf16, 1 = sigmoid -> bf16, 2 = store fp32.
// BROW: 1 = bias indexed by row (for transposed-output GEMMs), 0 = by col.
// 256 threads = 4 waves (2x2), tile 128x128, K-step 32, each wave 64x64 quad.
// LDS swizzle proven R7 (SQ_LDS_BANK_CONFLICT == 0 on HW).
template <int EPI, int TERMS, int BROW>
__launch_bounds__(256)
__global__ void mfma_gemm(const unsigned short* __restrict__ Ah,
                          const unsigned short* __restrict__ Al,
                          const unsigned short* __restrict__ Bth,
                          const unsigned short* __restrict__ Btl,
                          const float* __restrict__ bias,
                          unsigned short* __restrict__ Cb,
                          float* __restrict__ Cf,
                          int ldC) {
    constexpr int K = 1024;
    __shared__ alignas(16) unsigned short sAh[128][32];
    __shared__ alignas(16) unsigned short sBh[128][32];
    __shared__ alignas(16) unsigned short sAl[(TERMS == 3) ? 128 : 1][32];
    __shared__ alignas(16) unsigned short sBl[(TERMS == 3) ? 128 : 1][32];

    const int tid  = threadIdx.x;
    const int lane = tid & 63;
    const int wid  = tid >> 6;          // 0..3
    const int wr   = wid >> 1;          // 0..1
    const int wc   = wid & 1;

    const int m0 = blockIdx.y * 128;
    const int n0 = blockIdx.x * 128;

    const int srow = wid * 32 + (lane >> 2);
    const int scol = (((lane & 3) - ((lane >> 3) & 3)) & 3) * 8;  // inverse-swizzled src slice

    const unsigned short* gA = Ah + (size_t)(m0 + srow) * K + scol;
    const unsigned short* gB = Bth + (size_t)(n0 + srow) * K + scol;
    const unsigned short* gAl = (TERMS == 3) ? Al + (size_t)(m0 + srow) * K + scol : nullptr;
    const unsigned short* gBl = (TERMS == 3) ? Btl + (size_t)(n0 + srow) * K + scol : nullptr;

    const int r15 = lane & 15;
    const int csw = ((((lane >> 4) + (r15 >> 1)) & 3)) * 8;       // swizzled read slice

    f32x4 acc[4][4] = {};

    for (int k0 = 0; k0 < K; k0 += 32) {
        __syncthreads();
        GLOAD_LDS16(gA + k0,             &sAh[wid * 32][0]);
        GLOAD_LDS16(gA + 16 * K + k0,    &sAh[wid * 32 + 16][0]);
        GLOAD_LDS16(gB + k0,             &sBh[wid * 32][0]);
        GLOAD_LDS16(gB + 16 * K + k0,    &sBh[wid * 32 + 16][0]);
        if constexpr (TERMS == 3) {
            GLOAD_LDS16(gAl + k0,          &sAl[wid * 32][0]);
            GLOAD_LDS16(gAl + 16 * K + k0, &sAl[wid * 32 + 16][0]);
            GLOAD_LDS16(gBl + k0,          &sBl[wid * 32][0]);
            GLOAD_LDS16(gBl + 16 * K + k0, &sBl[wid * 32 + 16][0]);
        }
        __syncthreads();

        bf16x8 afh[4], bfh[4];
#pragma unroll
        for (int i = 0; i < 4; ++i) {
            afh[i] = *(const bf16x8*)&sAh[wr * 64 + i * 16 + r15][csw];
            bfh[i] = *(const bf16x8*)&sBh[wc * 64 + i * 16 + r15][csw];
        }
        if constexpr (TERMS == 3) {
            bf16x8 afl[4], bfl[4];
#pragma unroll
            for (int i = 0; i < 4; ++i) {
                afl[i] = *(const bf16x8*)&sAl[wr * 64 + i * 16 + r15][csw];
                bfl[i] = *(const bf16x8*)&sBl[wc * 64 + i * 16 + r15][csw];
            }
#pragma unroll
            for (int mi = 0; mi < 4; ++mi)
#pragma unroll
                for (int ni = 0; ni < 4; ++ni) {
                    acc[mi][ni] = __builtin_amdgcn_mfma_f32_16x16x32_bf16(afh[mi], bfh[ni], acc[mi][ni], 0, 0, 0);
                    acc[mi][ni] = __builtin_amdgcn_mfma_f32_16x16x32_bf16(afh[mi], bfl[ni], acc[mi][ni], 0, 0, 0);
                    acc[mi][ni] = __builtin_amdgcn_mfma_f32_16x16x32_bf16(afl[mi], bfh[ni], acc[mi][ni], 0, 0, 0);
                }
        } else {
#pragma unroll
            for (int mi = 0; mi < 4; ++mi)
#pragma unroll
                for (int ni = 0; ni < 4; ++ni)
                    acc[mi][ni] = __builtin_amdgcn_mfma_f32_16x16x32_bf16(afh[mi], bfh[ni], acc[mi][ni], 0, 0, 0);
        }
    }

    // epilogue: C/D layout col = lane&15, row = (lane>>4)*4 + j  [m89/m91]
    const int colb = n0 + wc * 64 + (lane & 15);
    const int rowb = m0 + wr * 64 + (lane >> 4) * 4;
#pragma unroll
    for (int ni = 0; ni < 4; ++ni) {
        const int col = colb + ni * 16;
        const float bcol = BROW ? 0.f : bias[col];
#pragma unroll
        for (int mi = 0; mi < 4; ++mi) {
#pragma unroll
            for (int j = 0; j < 4; ++j) {
                const int row = rowb + mi * 16 + j;
                float o = acc[mi][ni][j] + (BROW ? bias[row] : bcol);
                if constexpr (EPI == 1) o = 1.0f / (1.0f + expf(-o));
                if constexpr (EPI == 2) Cf[(size_t)row * ldC + col] = o;
                else                    Cb[(size_t)row * ldC + col] = f2bf(o);
            }
        }
    }
}

// --- attention, transposed layout, d-SPLIT across the block's 4 waves.
// Block = (head h, 64 consecutive n's); wave w owns d in [16w, 16w+16).
// Grid 1024 blocks -> 4096 waves (4/SIMD avg) vs attn3's 1024 (1/SIMD):
// fixes the R9 latency-bound profile (VALUBusy 8.5%, Occ 9.6%).
// QK partials reduced via LDS (stride 25 => conflict-free); softmax
// recomputed per wave (cheap); PV has no cross-wave dependency.
// In-place JT_hi over q rows stays safe: wave w writes only the q-rows
// that wave w itself read, after its own QK phase + barrier.
__launch_bounds__(256)
__global__ void attn4(unsigned short* __restrict__ qkvT,
                      const unsigned short* __restrict__ gateT,
                      const float* __restrict__ pos_bias,
                      unsigned short* __restrict__ JTlo) {
    __shared__ float red[4][64][NDIS + 1];   // +1 pad: stride 25, coprime 32
    const int wid  = threadIdx.x >> 6;
    const int lane = threadIdx.x & 63;
    const int h  = blockIdx.x >> 6;     // 0..15
    const int nt = blockIdx.x & 63;     // 0..63
    const int n  = nt * 64 + lane;

    const size_t qrow = (size_t)(h * HDIM) * SEQ;
    const size_t krow = (size_t)(DIM + h * HDIM) * SEQ;
    const size_t vrow = (size_t)(2 * DIM + h * HDIM) * SEQ;

    int idx[NDIS];
#pragma unroll
    for (int dd = 0; dd < NDIS; ++dd) idx[dd] = (n >= DOFF[dd]) ? (n - DOFF[dd]) : 0;

    float dots[NDIS];
#pragma unroll
    for (int dd = 0; dd < NDIS; ++dd) dots[dd] = 0.f;

    // QK over this wave's d-slice: per d, 1 + 24 coalesced loads, 24 indep FMA chains
    const int d0 = wid * 16;
    for (int d = d0; d < d0 + 16; ++d) {
        const float qd = bf2f(qkvT[qrow + (size_t)d * SEQ + n]);
        const unsigned short* kp = qkvT + krow + (size_t)d * SEQ;
#pragma unroll
        for (int dd = 0; dd < NDIS; ++dd)
            dots[dd] = fmaf(qd, bf2f(kp[idx[dd]]), dots[dd]);
    }

    // cross-wave reduction of the 24 partial dots
#pragma unroll
    for (int dd = 0; dd < NDIS; ++dd) red[wid][lane][dd] = dots[dd];
    __syncthreads();
#pragma unroll
    for (int dd = 0; dd < NDIS; ++dd)
        dots[dd] = red[0][lane][dd] + red[1][lane][dd] + red[2][lane][dd] + red[3][lane][dd];

    // zero dots where offset exceeds n (reference: zero-padded shift -> dot = 0)
#pragma unroll
    for (int dd = 0; dd < NDIS; ++dd) if (n < DOFF[dd]) dots[dd] = 0.f;

    // lane-private softmax over the 44 taps (redundant per wave, cheap)
    const float scale = 0.125f;
    float mx = -1e30f;
#pragma unroll
    for (int o = 0; o < NOFF; ++o)
        mx = fmaxf(mx, fmaf(dots[MAP[o]], scale, pos_bias[o * NHEAD + h]));
    float Z = 0.f;
    float W[NDIS];
#pragma unroll
    for (int dd = 0; dd < NDIS; ++dd) W[dd] = 0.f;
#pragma unroll
    for (int o = 0; o < NOFF; ++o) {
        const float e = expf(fmaf(dots[MAP[o]], scale, pos_bias[o * NHEAD + h]) - mx);
        Z += e;
        W[MAP[o]] += e;
    }
    const float invZ = 1.0f / Z;
#pragma unroll
    for (int dd = 0; dd < NDIS; ++dd) W[dd] = (n >= DOFF[dd]) ? W[dd] * invZ : 0.f;

    // PV + gate + hi/lo split over this wave's d-slice (no cross-wave dep)
    for (int d = d0; d < d0 + 16; ++d) {
        const unsigned short* vp = qkvT + vrow + (size_t)d * SEQ;
        float od = 0.f;
#pragma unroll
        for (int dd = 0; dd < NDIS; ++dd)
            od = fmaf(W[dd], bf2f(vp[idx[dd]]), od);
        const float g = bf2f(gateT[qrow + (size_t)d * SEQ + n]);
        const float j = od * g;
        const unsigned short hi = f2bf(j);
        qkvT[qrow + (size_t)d * SEQ + n] = hi;
        JTlo[qrow + (size_t)d * SEQ + n] = f2bf(j - bf2f(hi));
    }
}

// --- transpose [1024][4096] -> [4096][1024] bf16, two buffer pairs (hi, lo).
// 64x64 tiles via LDS with XOR-swizzle (c>>3) -> ~2-way banks both phases.
__launch_bounds__(256)
__global__ void transpose_cn(const unsigned short* __restrict__ srcA, unsigned short* __restrict__ dstA,
                             const unsigned short* __restrict__ srcB, unsigned short* __restrict__ dstB) {
    __shared__ unsigned short t[64 * 64];
    const unsigned short* src = blockIdx.z ? srcB : srcA;
    unsigned short*       dst = blockIdx.z ? dstB : dstA;
    const int n0 = blockIdx.x * 64;
    const int c0 = blockIdx.y * 64;
    const int tt = threadIdx.x;
    {
        const int cr = tt >> 2;            // source row (c), 0..63
        const int nn = (tt & 3) * 16;      // source col start (n)
        const unsigned short* p = src + (size_t)(c0 + cr) * SEQ + n0 + nn;
        const u16x8 a = *(const u16x8*)p;
        const u16x8 b = *(const u16x8*)(p + 8);
        const int swz = (cr >> 3) & 7;
        *(u16x8*)&t[cr * 64 + (((nn >> 3) ^ swz) << 3)]       = a;
        *(u16x8*)&t[cr * 64 + ((((nn >> 3) + 1) ^ swz) << 3)] = b;
    }
    __syncthreads();
    {
        const int nr = tt >> 2;            // dst row (n), 0..63
        const int cc = (tt & 3) * 16;      // dst col start (c)
        u16x8 r0, r1;
#pragma unroll
        for (int j = 0; j < 8; ++j) {
            const int c = cc + j;
            r0[j] = t[c * 64 + ((((nr >> 3) ^ ((c >> 3) & 7)) << 3) | (nr & 7))];
        }
#pragma unroll
        for (int j = 0; j < 8; ++j) {
            const int c = cc + 8 + j;
            r1[j] = t[c * 64 + ((((nr >> 3) ^ ((c >> 3) & 7)) << 3) | (nr & 7))];
        }
        unsigned short* q = dst + (size_t)(n0 + nr) * DIM + c0 + cc;
        *(u16x8*)q       = r0;
        *(u16x8*)(q + 8) = r1;
    }
}

// ===========================================================================
// FALLBACK PATH (proven R4 fp32 pipeline, needs 48 MB ws)
// ===========================================================================
#define BM 128
#define BN 128
#define BK 8

template <int MODE>
__launch_bounds__(256)
__global__ void gemm_k(const float* __restrict__ A, const float* __restrict__ A2,
                       const float* __restrict__ Bm, const float* __restrict__ bias,
                       float* __restrict__ C, int M, int Nn, int Kk,
                       int ldA, int ldB, int ldC) {
    __shared__ float As[BK][BM];
    __shared__ float Bs[BK][BN];
    const int tid = threadIdx.x;
    const int m0 = blockIdx.y * BM;
    const int n0 = blockIdx.x * BN;
    const int tx = tid & 15;
    const int ty = tid >> 4;
    float acc[8][8] = {};
    const int arow = tid >> 1;
    const int ac4  = (tid & 1) * 4;
    const int brow = tid >> 5;
    const int bc4  = (tid & 31) * 4;
    const float* Aptr  = A + (size_t)(m0 + arow) * ldA + ac4;
    const float* A2ptr = (MODE == 2) ? (A2 + (size_t)(m0 + arow) * ldA + ac4) : nullptr;
    const float* Bptr  = Bm + (size_t)brow * ldB + n0 + bc4;
    for (int k0 = 0; k0 < Kk; k0 += BK) {
        float4 av = *(const float4*)(Aptr + k0);
        if constexpr (MODE == 2) {
            float4 gv = *(const float4*)(A2ptr + k0);
            av.x *= gv.x; av.y *= gv.y; av.z *= gv.z; av.w *= gv.w;
        }
        float4 bv = *(const float4*)(Bptr + (size_t)k0 * ldB);
        __syncthreads();
        As[ac4 + 0][arow] = av.x;
        As[ac4 + 1][arow] = av.y;
        As[ac4 + 2][arow] = av.z;
        As[ac4 + 3][arow] = av.w;
        *(float4*)&Bs[brow][bc4] = bv;
        __syncthreads();
#pragma unroll
        for (int kk = 0; kk < BK; ++kk) {
            float a[8], b[8];
            *(float4*)(a)     = *(const float4*)&As[kk][ty * 8];
            *(float4*)(a + 4) = *(const float4*)&As[kk][ty * 8 + 4];
            *(float4*)(b)     = *(const float4*)&Bs[kk][tx * 8];
            *(float4*)(b + 4) = *(const float4*)&Bs[kk][tx * 8 + 4];
#pragma unroll
            for (int i = 0; i < 8; ++i)
#pragma unroll
                for (int j = 0; j < 8; ++j)
                    acc[i][j] += a[i] * b[j];
        }
    }
#pragma unroll
    for (int i = 0; i < 8; ++i) {
        const int row = m0 + ty * 8 + i;
        float* Crow = C + (size_t)row * ldC + n0 + tx * 8;
#pragma unroll
        for (int j = 0; j < 8; ++j) {
            float v = acc[i][j] + bias[n0 + tx * 8 + j];
            if constexpr (MODE == 1) v = 1.0f / (1.0f + expf(-v));
            Crow[j] = v;
        }
    }
}

__launch_bounds__(256)
__global__ void attn_k(float* __restrict__ qkv, const float* __restrict__ pos_bias) {
    const float scale = 0.125f;
    const int w    = blockIdx.x * 4 + (threadIdx.x >> 6);
    const int lane = threadIdx.x & 63;
    const int n = w & (SEQ - 1);
    const int h = w >> 12;
    const size_t qidx = (size_t)n * (3 * DIM) + h * HDIM + lane;
    const float qv = qkv[qidx];
    const int kcol = DIM + h * HDIM + lane;
    const int vcol = 2 * DIM + h * HDIM + lane;
    float sc[NOFF];
#pragma unroll
    for (int o = 0; o < NOFF; ++o) {
        const int off = OFFS[o];
        const float pb = pos_bias[o * NHEAD + h];
        float s;
        if (off <= n) {
            float p = qv * qkv[(size_t)(n - off) * (3 * DIM) + kcol];
            p += __shfl_xor(p, 1);
            p += __shfl_xor(p, 2);
            p += __shfl_xor(p, 4);
            p += __shfl_xor(p, 8);
            p += __shfl_xor(p, 16);
            p += __shfl_xor(p, 32);
            s = p * scale + pb;
        } else s = pb;
        sc[o] = s;
    }
    float mx = sc[0];
#pragma unroll
    for (int o = 1; o < NOFF; ++o) mx = fmaxf(mx, sc[o]);
    float sum = 0.f;
#pragma unroll
    for (int o = 0; o < NOFF; ++o) { sc[o] = expf(sc[o] - mx); sum += sc[o]; }
    const float inv = 1.0f / sum;
    float acc = 0.f;
#pragma unroll
    for (int o = 0; o < NOFF; ++o) {
        const int off = OFFS[o];
        if (off <= n) acc += sc[o] * qkv[(size_t)(n - off) * (3 * DIM) + vcol];
    }
    qkv[qidx] = acc * inv;
}

// ===========================================================================
extern "C" void kernel_launch(void* const* d_in, const int* in_sizes, int n_in,
                              void* d_out, int out_size, void* d_ws, size_t ws_size,
                              hipStream_t stream) {
    const float* x        = (const float*)d_in[0];
    const float* w_qkv    = (const float*)d_in[1];
    const float* b_qkv    = (const float*)d_in[2];
    const float* w_out    = (const float*)d_in[3];
    const float* b_out    = (const float*)d_in[4];
    const float* w_gate   = (const float*)d_in[5];
    const float* b_gate   = (const float*)d_in[6];
    const float* pos_bias = (const float*)d_in[7];
    float* out = (float*)d_out;

    const size_t FAST_WS = 62914560ull;   // 60 MiB exactly (proven available in R7)

    if (ws_size >= FAST_WS) {
        // ---- fast path workspace (exactly 60 MiB) ----
        unsigned short* wqkvT  = (unsigned short*)d_ws;            // [3072][1024]  6 MiB
        unsigned short* wgateT = wqkvT  + (size_t)3072 * 1024;     // [1024][1024]  2 MiB
        unsigned short* woutTh = wgateT + (size_t)1024 * 1024;     //               2 MiB
        unsigned short* woutTl = woutTh + (size_t)1024 * 1024;     //               2 MiB
        unsigned short* xh     = woutTl + (size_t)1024 * 1024;     // [4096][1024]  8 MiB
        unsigned short* qkvT   = xh     + (size_t)4096 * 1024;     // [3072][4096] 24 MiB
        unsigned short* gateT  = qkvT   + (size_t)3072 * 4096;     // [1024][4096]  8 MiB
        unsigned short* JTlo   = gateT  + (size_t)1024 * 4096;     // [1024][4096]  8 MiB
        // post-attn aliases (source buffers dead by then):
        unsigned short* Jh = gateT;                      // [4096][1024] over gateT
        unsigned short* Jl = qkvT + (size_t)DIM * SEQ;   // [4096][1024] over kT rows

        prep_w<<<dim3(3072 / 32, 1024 / 32), 256, 0, stream>>>(w_qkv, wqkvT, nullptr, 3072);
        prep_w<<<dim3(1024 / 32, 1024 / 32), 256, 0, stream>>>(w_gate, wgateT, nullptr, 1024);
        prep_w<<<dim3(1024 / 32, 1024 / 32), 256, 0, stream>>>(w_out, woutTh, woutTl, 1024);

        for (int b = 0; b < BATCH; ++b) {
            const float* xb   = x   + (size_t)b * SEQ * DIM;
            float*       outb = out + (size_t)b * SEQ * DIM;

            split_x<<<4096, 256, 0, stream>>>(xb, xh);
            // qkvT[c][n] = wqkvT @ xh^T  (transposed-output GEMM, bias by row)
            mfma_gemm<0, 1, 1><<<dim3(4096 / 128, 3072 / 128), 256, 0, stream>>>(
                wqkvT, nullptr, xh, nullptr, b_qkv, qkvT, nullptr, 4096);
            // gateT[c][n] = sigmoid(wgateT @ xh^T + b_gate)
            mfma_gemm<1, 1, 1><<<dim3(4096 / 128, 1024 / 128), 256, 0, stream>>>(
                wgateT, nullptr, xh, nullptr, b_gate, gateT, nullptr, 4096);
            // attention (d-split, 1024 blocks): JT_hi in-place over q rows, JT_lo scratch
            attn4<<<1024, 256, 0, stream>>>(qkvT, gateT, pos_bias, JTlo);
            // JT (c-major) -> J (n-major) for the final GEMM
            transpose_cn<<<dim3(4096 / 64, 1024 / 64, 2), 256, 0, stream>>>(
                qkvT, Jh, JTlo, Jl);
            // out = J @ w_out + b_out  (3-term split, fp32 out)
            mfma_gemm<2, 3, 0><<<dim3(1024 / 128, 4096 / 128), 256, 0, stream>>>(
                Jh, Jl, woutTh, woutTl, b_out, nullptr, outb, 1024);
        }
    } else {
        // ---- proven fp32 fallback (R4), needs 48 MB ----
        const int Mb = SEQ;
        float* qkv_b = (float*)d_ws;
        for (int b = 0; b < BATCH; ++b) {
            const float* xb   = x   + (size_t)b * SEQ * DIM;
            float*       outb = out + (size_t)b * SEQ * DIM;
            gemm_k<0><<<dim3(3 * DIM / BN, Mb / BM), 256, 0, stream>>>(
                xb, nullptr, w_qkv, b_qkv, qkv_b, Mb, 3 * DIM, DIM, DIM, 3 * DIM, 3 * DIM);
            attn_k<<<(NHEAD * SEQ) / 4, 256, 0, stream>>>(qkv_b, pos_bias);
            gemm_k<1><<<dim3(DIM / BN, Mb / BM), 256, 0, stream>>>(
                xb, nullptr, w_gate, b_gate, qkv_b + DIM, Mb, DIM, DIM, DIM, DIM, 3 * DIM);
            gemm_k<2><<<dim3(DIM / BN, Mb / BM), 256, 0, stream>>>(
                qkv_b, qkv_b + DIM, w_out, b_out, outb, Mb, DIM, DIM, 3 * DIM, DIM, DIM);
        }
    }
}

// Round 11
// 1106.591 us; speedup vs baseline: 3.8721x; 1.0030x over previous
//
#include <hip/hip_runtime.h>
#include <hip/hip_bf16.h>
#include <cstddef>
#include <cstdint>

// Problem constants (B=4, N=4096, D=1024, H=16, HD=64, 44 dyadic offsets)
#define BATCH 4
#define SEQ   4096
#define DIM   1024
#define NHEAD 16
#define HDIM  64
#define NOFF  44
#define NDIS  24   // distinct offsets

static constexpr int OFFS[NOFF] = {
    0, 1, 2, 3,
    0, 2, 4, 6,
    0, 4, 8, 12,
    0, 8, 16, 24,
    0, 16, 32, 48,
    0, 32, 64, 96,
    0, 64, 128, 192,
    0, 128, 256, 384,
    0, 256, 512, 768,
    0, 512, 1024, 1536,
    0, 1024, 2048, 3072
};
static constexpr int DOFF[NDIS] = {
    0,1,2,3,4,6,8,12,16,24,32,48,64,96,128,192,256,384,512,768,1024,1536,2048,3072
};
static constexpr int MAP[NOFF] = {
    0,1,2,3,
    0,2,4,5,
    0,4,6,7,
    0,6,8,9,
    0,8,10,11,
    0,10,12,13,
    0,12,14,15,
    0,14,16,17,
    0,16,18,19,
    0,18,20,21,
    0,20,22,23
};

typedef short bf16x8 __attribute__((ext_vector_type(8)));
typedef float f32x4  __attribute__((ext_vector_type(4)));
typedef unsigned short u16x8 __attribute__((ext_vector_type(8)));

__device__ __forceinline__ unsigned short f2bf(float f) {
    unsigned int u = __float_as_uint(f);
    u += 0x7FFFu + ((u >> 16) & 1u);          // RNE
    return (unsigned short)(u >> 16);
}
__device__ __forceinline__ float bf2f(unsigned short h) {
    return __uint_as_float(((unsigned int)h) << 16);
}

#define GLOAD_LDS16(g, l)                                                     \
    __builtin_amdgcn_global_load_lds(                                         \
        (const __attribute__((address_space(1))) void*)(g),                   \
        (__attribute__((address_space(3))) void*)(l), 16, 0, 0)

// ===========================================================================
// FAST PATH
// ===========================================================================

// --- weight prep: W[K=1024][Nw] fp32  ->  WT_hi[Nw][1024] bf16 (+ optional lo)
__launch_bounds__(256)
__global__ void prep_w(const float* __restrict__ W, unsigned short* __restrict__ Th,
                       unsigned short* __restrict__ Tl, int Nw) {
    __shared__ float t[32][33];
    const int nb = blockIdx.x * 32;   // col tile in W
    const int kb = blockIdx.y * 32;   // row tile in W
    const int c  = threadIdx.x & 31;
    const int r0 = threadIdx.x >> 5;  // 0..7
#pragma unroll
    for (int i = 0; i < 4; ++i) {
        const int r = r0 + i * 8;
        t[r][c] = W[(size_t)(kb + r) * Nw + nb + c];
    }
    __syncthreads();
#pragma unroll
    for (int i = 0; i < 4; ++i) {
        const int rr = r0 + i * 8;                // row in T tile (col in W)
        const float v = t[c][rr];                 // = W[kb+c][nb+rr]
        const unsigned short h = f2bf(v);
        const size_t oidx = (size_t)(nb + rr) * 1024 + kb + c;
        Th[oidx] = h;
        if (Tl) Tl[oidx] = f2bf(v - bf2f(h));
    }
}

// --- x fp32 -> bf16 (hi only)
__launch_bounds__(256)
__global__ void split_x(const float* __restrict__ X, unsigned short* __restrict__ H) {
    const size_t i = ((size_t)blockIdx.x * 256 + threadIdx.x) * 4;
    const float4 v = *(const float4*)(X + i);
    ushort4 o;
    o.x = f2bf(v.x); o.y = f2bf(v.y); o.z = f2bf(v.z); o.w = f2bf(v.w);
    *(ushort4*)(H + i) = o;
}

// --- MFMA GEMM.  C[M,Nn] = A[M,1024] @ B^T[Nn,1024]^T + bias, all bf16 inputs.
// TERMS==3: 3-term split (Ah+Al)(Bh+Bl) minus lo*lo, fp32-class accuracy.
// EPI: 0 = store bf16, 1 = sigmoid -> bf16, 2 = store fp32.
// BROW: 1 = bias indexed by row (for transposed-output GEMMs), 0 = by col.
// 256 threads = 4 waves (2x2), tile 128x128, K-step 32, each wave 64x64 quad.
// LDS swizzle proven R7 (SQ_LDS_BANK_CONFLICT == 0 on HW).
template <int EPI, int TERMS, int BROW>
__launch_bounds__(256)
__global__ void mfma_gemm(const unsigned short* __restrict__ Ah,
                          const unsigned short* __restrict__ Al,
                          const unsigned short* __restrict__ Bth,
                          const unsigned short* __restrict__ Btl,
                          const float* __restrict__ bias,
                          unsigned short* __restrict__ Cb,
                          float* __restrict__ Cf,
                          int ldC) {
    constexpr int K = 1024;
    __shared__ alignas(16) unsigned short sAh[128][32];
    __shared__ alignas(16) unsigned short sBh[128][32];
    __shared__ alignas(16) unsigned short sAl[(TERMS == 3) ? 128 : 1][32];
    __shared__ alignas(16) unsigned short sBl[(TERMS == 3) ? 128 : 1][32];

    const int tid  = threadIdx.x;
    const int lane = tid & 63;
    const int wid  = tid >> 6;          // 0..3
    const int wr   = wid >> 1;          // 0..1
    const int wc   = wid & 1;

    const int m0 = blockIdx.y * 128;
    const int n0 = blockIdx.x * 128;

    const int srow = wid * 32 + (lane >> 2);
    const int scol = (((lane & 3) - ((lane >> 3) & 3)) & 3) * 8;  // inverse-swizzled src slice

    const unsigned short* gA = Ah + (size_t)(m0 + srow) * K + scol;
    const unsigned short* gB = Bth + (size_t)(n0 + srow) * K + scol;
    const unsigned short* gAl = (TERMS == 3) ? Al + (size_t)(m0 + srow) * K + scol : nullptr;
    const unsigned short* gBl = (TERMS == 3) ? Btl + (size_t)(n0 + srow) * K + scol : nullptr;

    const int r15 = lane & 15;
    const int csw = ((((lane >> 4) + (r15 >> 1)) & 3)) * 8;       // swizzled read slice

    f32x4 acc[4][4] = {};

    for (int k0 = 0; k0 < K; k0 += 32) {
        __syncthreads();
        GLOAD_LDS16(gA + k0,             &sAh[wid * 32][0]);
        GLOAD_LDS16(gA + 16 * K + k0,    &sAh[wid * 32 + 16][0]);
        GLOAD_LDS16(gB + k0,             &sBh[wid * 32][0]);
        GLOAD_LDS16(gB + 16 * K + k0,    &sBh[wid * 32 + 16][0]);
        if constexpr (TERMS == 3) {
            GLOAD_LDS16(gAl + k0,          &sAl[wid * 32][0]);
            GLOAD_LDS16(gAl + 16 * K + k0, &sAl[wid * 32 + 16][0]);
            GLOAD_LDS16(gBl + k0,          &sBl[wid * 32][0]);
            GLOAD_LDS16(gBl + 16 * K + k0, &sBl[wid * 32 + 16][0]);
        }
        __syncthreads();

        bf16x8 afh[4], bfh[4];
#pragma unroll
        for (int i = 0; i < 4; ++i) {
            afh[i] = *(const bf16x8*)&sAh[wr * 64 + i * 16 + r15][csw];
            bfh[i] = *(const bf16x8*)&sBh[wc * 64 + i * 16 + r15][csw];
        }
        if constexpr (TERMS == 3) {
            bf16x8 afl[4], bfl[4];
#pragma unroll
            for (int i = 0; i < 4; ++i) {
                afl[i] = *(const bf16x8*)&sAl[wr * 64 + i * 16 + r15][csw];
                bfl[i] = *(const bf16x8*)&sBl[wc * 64 + i * 16 + r15][csw];
            }
#pragma unroll
            for (int mi = 0; mi < 4; ++mi)
#pragma unroll
                for (int ni = 0; ni < 4; ++ni) {
                    acc[mi][ni] = __builtin_amdgcn_mfma_f32_16x16x32_bf16(afh[mi], bfh[ni], acc[mi][ni], 0, 0, 0);
                    acc[mi][ni] = __builtin_amdgcn_mfma_f32_16x16x32_bf16(afh[mi], bfl[ni], acc[mi][ni], 0, 0, 0);
                    acc[mi][ni] = __builtin_amdgcn_mfma_f32_16x16x32_bf16(afl[mi], bfh[ni], acc[mi][ni], 0, 0, 0);
                }
        } else {
#pragma unroll
            for (int mi = 0; mi < 4; ++mi)
#pragma unroll
                for (int ni = 0; ni < 4; ++ni)
                    acc[mi][ni] = __builtin_amdgcn_mfma_f32_16x16x32_bf16(afh[mi], bfh[ni], acc[mi][ni], 0, 0, 0);
        }
    }

    // epilogue: C/D layout col = lane&15, row = (lane>>4)*4 + j  [m89/m91]
    const int colb = n0 + wc * 64 + (lane & 15);
    const int rowb = m0 + wr * 64 + (lane >> 4) * 4;
#pragma unroll
    for (int ni = 0; ni < 4; ++ni) {
        const int col = colb + ni * 16;
        const float bcol = BROW ? 0.f : bias[col];
#pragma unroll
        for (int mi = 0; mi < 4; ++mi) {
#pragma unroll
            for (int j = 0; j < 4; ++j) {
                const int row = rowb + mi * 16 + j;
                float o = acc[mi][ni][j] + (BROW ? bias[row] : bcol);
                if constexpr (EPI == 1) o = 1.0f / (1.0f + expf(-o));
                if constexpr (EPI == 2) Cf[(size_t)row * ldC + col] = o;
                else                    Cb[(size_t)row * ldC + col] = f2bf(o);
            }
        }
    }
}

// --- attention, transposed layout, 8-way d-SPLIT, 512 threads (8 waves).
// Block = (head h, 64 consecutive n's); wave w owns d in [8w, 8w+8).
// Grid 1024 blocks x 8 waves = 8192 waves (8/SIMD), 4 blocks/CU = 2048 thr/CU
// = 100% theoretical occupancy (vs attn4's 16 waves/CU, measured Occ 21%).
// LDS kept at 4x64x25 floats (25.6 KB) via two-phase reduction:
//   phase A: waves 4..7 write red[w-4]; phase B: waves 0..3 += their partial;
//   phase C: all waves read red[0]+red[1]+red[2]+red[3].
// Stride 25 floats, gcd(25,32)=1 -> conflict-free.
// In-place JT_hi over q rows stays safe: wave w writes only the q-rows it
// alone read, after its QK phase + two barriers.
__launch_bounds__(512)
__global__ void attn5(unsigned short* __restrict__ qkvT,
                      const unsigned short* __restrict__ gateT,
                      const float* __restrict__ pos_bias,
                      unsigned short* __restrict__ JTlo) {
    __shared__ float red[4][64][NDIS + 1];
    const int wid  = threadIdx.x >> 6;   // 0..7
    const int lane = threadIdx.x & 63;
    const int h  = blockIdx.x >> 6;      // 0..15
    const int nt = blockIdx.x & 63;      // 0..63
    const int n  = nt * 64 + lane;

    const size_t qrow = (size_t)(h * HDIM) * SEQ;
    const size_t krow = (size_t)(DIM + h * HDIM) * SEQ;
    const size_t vrow = (size_t)(2 * DIM + h * HDIM) * SEQ;

    int idx[NDIS];
#pragma unroll
    for (int dd = 0; dd < NDIS; ++dd) idx[dd] = (n >= DOFF[dd]) ? (n - DOFF[dd]) : 0;

    float dots[NDIS];
#pragma unroll
    for (int dd = 0; dd < NDIS; ++dd) dots[dd] = 0.f;

    // QK over this wave's 8-d slice: per d, 1 + 24 coalesced loads, indep FMA chains
    const int d0 = wid * 8;
    for (int d = d0; d < d0 + 8; ++d) {
        const float qd = bf2f(qkvT[qrow + (size_t)d * SEQ + n]);
        const unsigned short* kp = qkvT + krow + (size_t)d * SEQ;
#pragma unroll
        for (int dd = 0; dd < NDIS; ++dd)
            dots[dd] = fmaf(qd, bf2f(kp[idx[dd]]), dots[dd]);
    }

    // two-phase cross-wave reduction (8 partials -> 4 slots -> sum)
    if (wid >= 4) {
#pragma unroll
        for (int dd = 0; dd < NDIS; ++dd) red[wid - 4][lane][dd] = dots[dd];
    }
    __syncthreads();
    if (wid < 4) {
#pragma unroll
        for (int dd = 0; dd < NDIS; ++dd) red[wid][lane][dd] += dots[dd];
    }
    __syncthreads();
#pragma unroll
    for (int dd = 0; dd < NDIS; ++dd)
        dots[dd] = red[0][lane][dd] + red[1][lane][dd] + red[2][lane][dd] + red[3][lane][dd];

    // zero dots where offset exceeds n (reference: zero-padded shift -> dot = 0)
#pragma unroll
    for (int dd = 0; dd < NDIS; ++dd) if (n < DOFF[dd]) dots[dd] = 0.f;

    // lane-private softmax over the 44 taps (redundant per wave, cheap)
    const float scale = 0.125f;
    float mx = -1e30f;
#pragma unroll
    for (int o = 0; o < NOFF; ++o)
        mx = fmaxf(mx, fmaf(dots[MAP[o]], scale, pos_bias[o * NHEAD + h]));
    float Z = 0.f;
    float W[NDIS];
#pragma unroll
    for (int dd = 0; dd < NDIS; ++dd) W[dd] = 0.f;
#pragma unroll
    for (int o = 0; o < NOFF; ++o) {
        const float e = expf(fmaf(dots[MAP[o]], scale, pos_bias[o * NHEAD + h]) - mx);
        Z += e;
        W[MAP[o]] += e;
    }
    const float invZ = 1.0f / Z;
#pragma unroll
    for (int dd = 0; dd < NDIS; ++dd) W[dd] = (n >= DOFF[dd]) ? W[dd] * invZ : 0.f;

    // PV + gate + hi/lo split over this wave's 8-d slice (no cross-wave dep)
    for (int d = d0; d < d0 + 8; ++d) {
        const unsigned short* vp = qkvT + vrow + (size_t)d * SEQ;
        float od = 0.f;
#pragma unroll
        for (int dd = 0; dd < NDIS; ++dd)
            od = fmaf(W[dd], bf2f(vp[idx[dd]]), od);
        const float g = bf2f(gateT[qrow + (size_t)d * SEQ + n]);
        const float j = od * g;
        const unsigned short hi = f2bf(j);
        qkvT[qrow + (size_t)d * SEQ + n] = hi;
        JTlo[qrow + (size_t)d * SEQ + n] = f2bf(j - bf2f(hi));
    }
}

// --- transpose [1024][4096] -> [4096][1024] bf16, two buffer pairs (hi, lo).
// 64x64 tiles via LDS with XOR-swizzle (c>>3) -> ~2-way banks both phases.
__launch_bounds__(256)
__global__ void transpose_cn(const unsigned short* __restrict__ srcA, unsigned short* __restrict__ dstA,
                             const unsigned short* __restrict__ srcB, unsigned short* __restrict__ dstB) {
    __shared__ unsigned short t[64 * 64];
    const unsigned short* src = blockIdx.z ? srcB : srcA;
    unsigned short*       dst = blockIdx.z ? dstB : dstA;
    const int n0 = blockIdx.x * 64;
    const int c0 = blockIdx.y * 64;
    const int tt = threadIdx.x;
    {
        const int cr = tt >> 2;            // source row (c), 0..63
        const int nn = (tt & 3) * 16;      // source col start (n)
        const unsigned short* p = src + (size_t)(c0 + cr) * SEQ + n0 + nn;
        const u16x8 a = *(const u16x8*)p;
        const u16x8 b = *(const u16x8*)(p + 8);
        const int swz = (cr >> 3) & 7;
        *(u16x8*)&t[cr * 64 + (((nn >> 3) ^ swz) << 3)]       = a;
        *(u16x8*)&t[cr * 64 + ((((nn >> 3) + 1) ^ swz) << 3)] = b;
    }
    __syncthreads();
    {
        const int nr = tt >> 2;            // dst row (n), 0..63
        const int cc = (tt & 3) * 16;      // dst col start (c)
        u16x8 r0, r1;
#pragma unroll
        for (int j = 0; j < 8; ++j) {
            const int c = cc + j;
            r0[j] = t[c * 64 + ((((nr >> 3) ^ ((c >> 3) & 7)) << 3) | (nr & 7))];
        }
#pragma unroll
        for (int j = 0; j < 8; ++j) {
            const int c = cc + 8 + j;
            r1[j] = t[c * 64 + ((((nr >> 3) ^ ((c >> 3) & 7)) << 3) | (nr & 7))];
        }
        unsigned short* q = dst + (size_t)(n0 + nr) * DIM + c0 + cc;
        *(u16x8*)q       = r0;
        *(u16x8*)(q + 8) = r1;
    }
}

// ===========================================================================
// FALLBACK PATH (proven R4 fp32 pipeline, needs 48 MB ws)
// ===========================================================================
#define BM 128
#define BN 128
#define BK 8

template <int MODE>
__launch_bounds__(256)
__global__ void gemm_k(const float* __restrict__ A, const float* __restrict__ A2,
                       const float* __restrict__ Bm, const float* __restrict__ bias,
                       float* __restrict__ C, int M, int Nn, int Kk,
                       int ldA, int ldB, int ldC) {
    __shared__ float As[BK][BM];
    __shared__ float Bs[BK][BN];
    const int tid = threadIdx.x;
    const int m0 = blockIdx.y * BM;
    const int n0 = blockIdx.x * BN;
    const int tx = tid & 15;
    const int ty = tid >> 4;
    float acc[8][8] = {};
    const int arow = tid >> 1;
    const int ac4  = (tid & 1) * 4;
    const int brow = tid >> 5;
    const int bc4  = (tid & 31) * 4;
    const float* Aptr  = A + (size_t)(m0 + arow) * ldA + ac4;
    const float* A2ptr = (MODE == 2) ? (A2 + (size_t)(m0 + arow) * ldA + ac4) : nullptr;
    const float* Bptr  = Bm + (size_t)brow * ldB + n0 + bc4;
    for (int k0 = 0; k0 < Kk; k0 += BK) {
        float4 av = *(const float4*)(Aptr + k0);
        if constexpr (MODE == 2) {
            float4 gv = *(const float4*)(A2ptr + k0);
            av.x *= gv.x; av.y *= gv.y; av.z *= gv.z; av.w *= gv.w;
        }
        float4 bv = *(const float4*)(Bptr + (size_t)k0 * ldB);
        __syncthreads();
        As[ac4 + 0][arow] = av.x;
        As[ac4 + 1][arow] = av.y;
        As[ac4 + 2][arow] = av.z;
        As[ac4 + 3][arow] = av.w;
        *(float4*)&Bs[brow][bc4] = bv;
        __syncthreads();
#pragma unroll
        for (int kk = 0; kk < BK; ++kk) {
            float a[8], b[8];
            *(float4*)(a)     = *(const float4*)&As[kk][ty * 8];
            *(float4*)(a + 4) = *(const float4*)&As[kk][ty * 8 + 4];
            *(float4*)(b)     = *(const float4*)&Bs[kk][tx * 8];
            *(float4*)(b + 4) = *(const float4*)&Bs[kk][tx * 8 + 4];
#pragma unroll
            for (int i = 0; i < 8; ++i)
#pragma unroll
                for (int j = 0; j < 8; ++j)
                    acc[i][j] += a[i] * b[j];
        }
    }
#pragma unroll
    for (int i = 0; i < 8; ++i) {
        const int row = m0 + ty * 8 + i;
        float* Crow = C + (size_t)row * ldC + n0 + tx * 8;
#pragma unroll
        for (int j = 0; j < 8; ++j) {
            float v = acc[i][j] + bias[n0 + tx * 8 + j];
            if constexpr (MODE == 1) v = 1.0f / (1.0f + expf(-v));
            Crow[j] = v;
        }
    }
}

__launch_bounds__(256)
__global__ void attn_k(float* __restrict__ qkv, const float* __restrict__ pos_bias) {
    const float scale = 0.125f;
    const int w    = blockIdx.x * 4 + (threadIdx.x >> 6);
    const int lane = threadIdx.x & 63;
    const int n = w & (SEQ - 1);
    const int h = w >> 12;
    const size_t qidx = (size_t)n * (3 * DIM) + h * HDIM + lane;
    const float qv = qkv[qidx];
    const int kcol = DIM + h * HDIM + lane;
    const int vcol = 2 * DIM + h * HDIM + lane;
    float sc[NOFF];
#pragma unroll
    for (int o = 0; o < NOFF; ++o) {
        const int off = OFFS[o];
        const float pb = pos_bias[o * NHEAD + h];
        float s;
        if (off <= n) {
            float p = qv * qkv[(size_t)(n - off) * (3 * DIM) + kcol];
            p += __shfl_xor(p, 1);
            p += __shfl_xor(p, 2);
            p += __shfl_xor(p, 4);
            p += __shfl_xor(p, 8);
            p += __shfl_xor(p, 16);
            p += __shfl_xor(p, 32);
            s = p * scale + pb;
        } else s = pb;
        sc[o] = s;
    }
    float mx = sc[0];
#pragma unroll
    for (int o = 1; o < NOFF; ++o) mx = fmaxf(mx, sc[o]);
    float sum = 0.f;
#pragma unroll
    for (int o = 0; o < NOFF; ++o) { sc[o] = expf(sc[o] - mx); sum += sc[o]; }
    const float inv = 1.0f / sum;
    float acc = 0.f;
#pragma unroll
    for (int o = 0; o < NOFF; ++o) {
        const int off = OFFS[o];
        if (off <= n) acc += sc[o] * qkv[(size_t)(n - off) * (3 * DIM) + vcol];
    }
    qkv[qidx] = acc * inv;
}

// ===========================================================================
extern "C" void kernel_launch(void* const* d_in, const int* in_sizes, int n_in,
                              void* d_out, int out_size, void* d_ws, size_t ws_size,
                              hipStream_t stream) {
    const float* x        = (const float*)d_in[0];
    const float* w_qkv    = (const float*)d_in[1];
    const float* b_qkv    = (const float*)d_in[2];
    const float* w_out    = (const float*)d_in[3];
    const float* b_out    = (const float*)d_in[4];
    const float* w_gate   = (const float*)d_in[5];
    const float* b_gate   = (const float*)d_in[6];
    const float* pos_bias = (const float*)d_in[7];
    float* out = (float*)d_out;

    const size_t FAST_WS = 62914560ull;   // 60 MiB exactly (proven available in R7)

    if (ws_size >= FAST_WS) {
        // ---- fast path workspace (exactly 60 MiB) ----
        unsigned short* wqkvT  = (unsigned short*)d_ws;            // [3072][1024]  6 MiB
        unsigned short* wgateT = wqkvT  + (size_t)3072 * 1024;     // [1024][1024]  2 MiB
        unsigned short* woutTh = wgateT + (size_t)1024 * 1024;     //               2 MiB
        unsigned short* woutTl = woutTh + (size_t)1024 * 1024;     //               2 MiB
        unsigned short* xh     = woutTl + (size_t)1024 * 1024;     // [4096][1024]  8 MiB
        unsigned short* qkvT   = xh     + (size_t)4096 * 1024;     // [3072][4096] 24 MiB
        unsigned short* gateT  = qkvT   + (size_t)3072 * 4096;     // [1024][4096]  8 MiB
        unsigned short* JTlo   = gateT  + (size_t)1024 * 4096;     // [1024][4096]  8 MiB
        // post-attn aliases (source buffers dead by then):
        unsigned short* Jh = gateT;                      // [4096][1024] over gateT
        unsigned short* Jl = qkvT + (size_t)DIM * SEQ;   // [4096][1024] over kT rows

        prep_w<<<dim3(3072 / 32, 1024 / 32), 256, 0, stream>>>(w_qkv, wqkvT, nullptr, 3072);
        prep_w<<<dim3(1024 / 32, 1024 / 32), 256, 0, stream>>>(w_gate, wgateT, nullptr, 1024);
        prep_w<<<dim3(1024 / 32, 1024 / 32), 256, 0, stream>>>(w_out, woutTh, woutTl, 1024);

        for (int b = 0; b < BATCH; ++b) {
            const float* xb   = x   + (size_t)b * SEQ * DIM;
            float*       outb = out + (size_t)b * SEQ * DIM;

            split_x<<<4096, 256, 0, stream>>>(xb, xh);
            // qkvT[c][n] = wqkvT @ xh^T  (transposed-output GEMM, bias by row)
            mfma_gemm<0, 1, 1><<<dim3(4096 / 128, 3072 / 128), 256, 0, stream>>>(
                wqkvT, nullptr, xh, nullptr, b_qkv, qkvT, nullptr, 4096);
            // gateT[c][n] = sigmoid(wgateT @ xh^T + b_gate)
            mfma_gemm<1, 1, 1><<<dim3(4096 / 128, 1024 / 128), 256, 0, stream>>>(
                wgateT, nullptr, xh, nullptr, b_gate, gateT, nullptr, 4096);
            // attention (8-way d-split, 512 threads): JT_hi in-place, JT_lo scratch
            attn5<<<1024, 512, 0, stream>>>(qkvT, gateT, pos_bias, JTlo);
            // JT (c-major) -> J (n-major) for the final GEMM
            transpose_cn<<<dim3(4096 / 64, 1024 / 64, 2), 256, 0, stream>>>(
                qkvT, Jh, JTlo, Jl);
            // out = J @ w_out + b_out  (3-term split, fp32 out)
            mfma_gemm<2, 3, 0><<<dim3(1024 / 128, 4096 / 128), 256, 0, stream>>>(
                Jh, Jl, woutTh, woutTl, b_out, nullptr, outb, 1024);
        }
    } else {
        // ---- proven fp32 fallback (R4), needs 48 MB ----
        const int Mb = SEQ;
        float* qkv_b = (float*)d_ws;
        for (int b = 0; b < BATCH; ++b) {
            const float* xb   = x   + (size_t)b * SEQ * DIM;
            float*       outb = out + (size_t)b * SEQ * DIM;
            gemm_k<0><<<dim3(3 * DIM / BN, Mb / BM), 256, 0, stream>>>(
                xb, nullptr, w_qkv, b_qkv, qkv_b, Mb, 3 * DIM, DIM, DIM, 3 * DIM, 3 * DIM);
            attn_k<<<(NHEAD * SEQ) / 4, 256, 0, stream>>>(qkv_b, pos_bias);
            gemm_k<1><<<dim3(DIM / BN, Mb / BM), 256, 0, stream>>>(
                xb, nullptr, w_gate, b_gate, qkv_b + DIM, Mb, DIM, DIM, DIM, DIM, 3 * DIM);
            gemm_k<2><<<dim3(DIM / BN, Mb / BM), 256, 0, stream>>>(
                qkv_b, qkv_b + DIM, w_out, b_out, outb, Mb, DIM, DIM, 3 * DIM, DIM, DIM);
        }
    }
}